// Round 10
// baseline (317.379 us; speedup 1.0000x reference)
//
#include <hip/hip_runtime.h>
#include <stdint.h>

// GraphConv x5 on MI355X — round 29.
// vs round 28 (297.6us; k_aggfused 49.7us, 5th flat schedule variant):
// remaining hypotheses: (a) cross-iteration latency exposure (every iter
// still drains its own gathers; nothing spans the loop back-edge) vs
// (b) TA/TCP gather-request-rate bound. Discriminator: TRUE depth-1
// software pipeline — double-buffered 16KB stage; steady-state iter =
// vmcnt(8) [pairs_{i+1}, ~0 stall] -> issue iter i+1's 9 loads into alt
// buffer -> masks -> vmcnt(9) [iter i's gathers, issued a full iteration
// ago] -> consume. Wave-uniform tail branch (last iter vmcnt(0));
// vmcnt(0) after loop before sH overlay. If flat, (b) is confirmed and
// next round halves request count via fp8 G rows.

#define NN 100000
#define NE 1600000
#define HID 64
#define NBKT 391            // ceil(NN/256), bucket = dst >> 8
#define CAP 8192            // padded bucket capacity (mean 4092, +64 sigma)
#define PMAX (NBKT * CAP)
#define TILE 4096
#define EPT 16              // TILE / 256
#define NTILE ((NE + TILE - 1) / TILE)   // 391

typedef __attribute__((ext_vector_type(8))) short bf16x8;
typedef __attribute__((ext_vector_type(4))) float f32x4;
typedef __attribute__((ext_vector_type(2))) unsigned int u32x2;
typedef __attribute__((ext_vector_type(4))) unsigned int u32x4;

__device__ __forceinline__ uint32_t rne_bf16(float v) {
    uint32_t u = __float_as_uint(v);
    return (u + 0x7fffu + ((u >> 16) & 1u)) >> 16;
}

// ---------------- CSR build ----------------

// tile-local LDS counting sort + coalesced segment write-out
__global__ __launch_bounds__(256) void k_bpart(const int* __restrict__ src,
                                               const int* __restrict__ dst,
                                               const float* __restrict__ w,
                                               int* __restrict__ bcur,
                                               int2* __restrict__ bpairs) {
    __shared__ int  hcnt[NBKT];      // count, then cursor
    __shared__ int  hoff[NBKT];      // local exclusive offset
    __shared__ int  hadj[NBKT];      // global base - local offset
    __shared__ int  sc0[512];
    __shared__ int  sc1[512];
    __shared__ int2 sT[TILE];        // 32 KB staged tile (bucket-sorted)
    __shared__ int  sAdj[TILE];      // 16 KB per-slot global adjust
    int tile0 = blockIdx.x * TILE;
    int t = threadIdx.x;
    for (int i = t; i < NBKT; i += 256) hcnt[i] = 0;
    __syncthreads();

    int   pk[EPT];
    int   bk[EPT];
    float wv[EPT];
    #pragma unroll
    for (int k = 0; k < EPT; k++) {
        int e = tile0 + t + k * 256;
        if (e < NE) {
            int d = dst[e];
            int b = d >> 8;
            pk[k] = (src[e] << 8) | (d & 255);
            wv[k] = w[e];
            bk[k] = b;
            atomicAdd(&hcnt[b], 1);
        } else {
            bk[k] = -1;
        }
    }
    __syncthreads();

    // inclusive scan of hcnt over 512 (padded) with ping-pong buffers
    sc0[t]       = (t < NBKT) ? hcnt[t] : 0;
    sc0[t + 256] = (t + 256 < NBKT) ? hcnt[t + 256] : 0;
    __syncthreads();
    int* cur = sc0;
    int* oth = sc1;
    for (int off = 1; off < 512; off <<= 1) {
        int v0 = cur[t]       + ((t       >= off) ? cur[t - off]       : 0);
        int v1 = cur[t + 256] + ((t + 256 >= off) ? cur[t + 256 - off] : 0);
        oth[t] = v0;
        oth[t + 256] = v1;
        __syncthreads();
        int* tmp = cur; cur = oth; oth = tmp;
    }
    for (int i = t; i < NBKT; i += 256) {
        int c = hcnt[i];
        int excl = cur[i] - c;
        hoff[i] = excl;
        int gbase = c ? atomicAdd(&bcur[i], c) : 0;
        hadj[i] = gbase - excl;
        hcnt[i] = 0;                 // reuse as local cursor
    }
    __syncthreads();

    // scatter into LDS (bucket-sorted order)
    #pragma unroll
    for (int k = 0; k < EPT; k++) {
        if (bk[k] >= 0) {
            int b = bk[k];
            int pos = hoff[b] + atomicAdd(&hcnt[b], 1);
            sT[pos] = make_int2(pk[k], __float_as_int(wv[k]));
            sAdj[pos] = hadj[b];
        }
    }
    __syncthreads();

    // linear write-out: consecutive slots in a bucket run -> consecutive
    // global addresses (coalesced bursts)
    int n = NE - tile0; if (n > TILE) n = TILE;
    for (int j = t; j < n; j += 256)
        bpairs[sAdj[j] + j] = sT[j];
}

// one block per bucket: stage bucket in LDS, then LDS counting sort.
__global__ __launch_bounds__(256) void k_bcsr(const int* __restrict__ bcur,
                                              const int2* __restrict__ bpairs,
                                              int* __restrict__ offs,
                                              int* __restrict__ ends,
                                              uint32_t* __restrict__ pairs) {
    __shared__ int2 sE[CAP];        // 64 KB bucket stage
    __shared__ int cnt[256];
    __shared__ int scn[256];
    __shared__ int cur[256];
    int k = blockIdx.x, t = threadIdx.x;
    int base = k * CAP;
    int scnt = bcur[k] - base;
    cnt[t] = 0;
    __syncthreads();
    for (int j = t; j < scnt; j += 256) {
        int2 q = bpairs[base + j];
        sE[j] = q;
        atomicAdd(&cnt[q.x & 255], 1);
    }
    __syncthreads();
    int v = cnt[t], acc = v;
    scn[t] = v;
    __syncthreads();
    for (int off = 1; off < 256; off <<= 1) {
        int u = (t >= off) ? scn[t - off] : 0;
        __syncthreads();
        acc += u;
        scn[t] = acc;
        __syncthreads();
    }
    int excl = acc - v;
    cur[t] = excl;
    int d = (k << 8) + t;
    if (d < NN) {
        offs[d] = base + excl;
        ends[d] = base + excl + v;
    }
    __syncthreads();
    for (int j = t; j < scnt; j += 256) {
        int2 q = sE[j];
        int pos = base + atomicAdd(&cur[q.x & 255], 1);
        uint32_t wb = rne_bf16(__int_as_float(q.y)) & 0x7fffu;   // w >= 0
        pairs[pos] = (wb << 17) | (uint32_t)(q.x >> 8);
    }
}

// ---------------- weight hi/lo split (+ bucket cursor init) ----------------

__global__ __launch_bounds__(256) void k_wsplit(const float* __restrict__ Wrel_mid,
                                                const float* __restrict__ Wroot_mid,
                                                uint16_t* __restrict__ WgH,
                                                uint16_t* __restrict__ WgL,
                                                uint16_t* __restrict__ WrH,
                                                uint16_t* __restrict__ WrL,
                                                int* __restrict__ bcur) {
    int i = blockIdx.x * blockDim.x + threadIdx.x;
    if (i < NBKT) bcur[i] = i * CAP;
    if (i >= 3 * 4096) return;
    float a = Wrel_mid[i];
    uint32_t ah = rne_bf16(a);
    float al = a - __uint_as_float(ah << 16);
    WgH[i] = (uint16_t)ah;
    WgL[i] = (uint16_t)rne_bf16(al);
    float b = Wroot_mid[i];
    uint32_t bh = rne_bf16(b);
    float bl = b - __uint_as_float(bh << 16);
    WrH[i] = (uint16_t)bh;
    WrL[i] = (uint16_t)rne_bf16(bl);
}

// ---------------- block-level epilogue helpers (k_l0pre only) --------------

__device__ __forceinline__ void mfma_epilogue(
        int lane, int w, const uint32_t* sH,
        const uint16_t* __restrict__ WgH, const uint16_t* __restrict__ WgL,
        const uint16_t* __restrict__ WrH, const uint16_t* __restrict__ WrL,
        const float* __restrict__ brel,
        uint16_t* sG, uint16_t* sR) {
    int row = lane & 15;
    int quad = lane >> 4;
    int kb = quad * 8;
    bf16x8 ah0 = *(const bf16x8*)&sH[row * 36 + quad * 4];
    bf16x8 ah1 = *(const bf16x8*)&sH[row * 36 + 16 + quad * 4];
    int oc = w * 16 + row;
    {
        bf16x8 bh0 = *(const bf16x8*)&WgH[oc * 64 + kb];
        bf16x8 bh1 = *(const bf16x8*)&WgH[oc * 64 + 32 + kb];
        bf16x8 bl0 = *(const bf16x8*)&WgL[oc * 64 + kb];
        bf16x8 bl1 = *(const bf16x8*)&WgL[oc * 64 + 32 + kb];
        f32x4 acc = {0.f, 0.f, 0.f, 0.f};
        acc = __builtin_amdgcn_mfma_f32_16x16x32_bf16(ah0, bh0, acc, 0, 0, 0);
        acc = __builtin_amdgcn_mfma_f32_16x16x32_bf16(ah1, bh1, acc, 0, 0, 0);
        acc = __builtin_amdgcn_mfma_f32_16x16x32_bf16(ah0, bl0, acc, 0, 0, 0);
        acc = __builtin_amdgcn_mfma_f32_16x16x32_bf16(ah1, bl1, acc, 0, 0, 0);
        #pragma unroll
        for (int r = 0; r < 4; r++)
            sG[(quad * 4 + r) * 68 + oc] = (uint16_t)rne_bf16(acc[r]);
    }
    {
        bf16x8 bh0 = *(const bf16x8*)&WrH[oc * 64 + kb];
        bf16x8 bh1 = *(const bf16x8*)&WrH[oc * 64 + 32 + kb];
        bf16x8 bl0 = *(const bf16x8*)&WrL[oc * 64 + kb];
        bf16x8 bl1 = *(const bf16x8*)&WrL[oc * 64 + 32 + kb];
        float bias = brel[oc];
        f32x4 acc = {bias, bias, bias, bias};
        acc = __builtin_amdgcn_mfma_f32_16x16x32_bf16(ah0, bh0, acc, 0, 0, 0);
        acc = __builtin_amdgcn_mfma_f32_16x16x32_bf16(ah1, bh1, acc, 0, 0, 0);
        acc = __builtin_amdgcn_mfma_f32_16x16x32_bf16(ah0, bl0, acc, 0, 0, 0);
        acc = __builtin_amdgcn_mfma_f32_16x16x32_bf16(ah1, bl1, acc, 0, 0, 0);
        #pragma unroll
        for (int r = 0; r < 4; r++)
            sR[(quad * 4 + r) * 68 + oc] = (uint16_t)rne_bf16(acc[r]);
    }
}

__device__ __forceinline__ void epilogue_writeout(
        int tid, int blk16, const uint16_t* sG, const uint16_t* sR,
        uint16_t* __restrict__ Gout, uint16_t* __restrict__ Rout) {
    const uint32_t* sGd = (const uint32_t*)sG;   // stride 34 dwords/node
    const uint32_t* sRd = (const uint32_t*)sR;
    uint32_t* Gd = (uint32_t*)Gout;
    uint32_t* Rd = (uint32_t*)Rout;
    #pragma unroll
    for (int it = 0; it < 2; it++) {
        int idx = it * 256 + tid;
        int nd = idx >> 5, col = idx & 31;
        Gd[(blk16 + nd) * 32 + col] = sGd[nd * 34 + col];
        Rd[(blk16 + nd) * 32 + col] = sRd[nd * 34 + col];
    }
}

// ---------------- layers ----------------

// layer 0 (fused): edge-parallel aggregation (all waves, shfl reduce), then
// h0 = relu(...) staged in LDS, MFMA epilogue -> G1,R1.
__global__ __launch_bounds__(256) void k_l0pre(
        const int* __restrict__ offs, const int* __restrict__ ends,
        const uint32_t* __restrict__ pairs, const float* __restrict__ x,
        const float* __restrict__ Wrel0, const float* __restrict__ brel0,
        const float* __restrict__ Wroot0,
        const uint16_t* __restrict__ WgH, const uint16_t* __restrict__ WgL,
        const uint16_t* __restrict__ WrH, const uint16_t* __restrict__ WrL,
        const float* __restrict__ brel,
        uint16_t* __restrict__ Gout, uint16_t* __restrict__ Rout) {
    __shared__ uint32_t sH[16 * 36];
    __shared__ uint16_t sG[16 * 68];
    __shared__ uint16_t sR[16 * 68];
    int c = threadIdx.x & 63;
    int w = threadIdx.x >> 6;
    int blk16 = blockIdx.x * 16;
    float agg[4];
    #pragma unroll
    for (int t = 0; t < 4; t++) {
        int node = blk16 + w * 4 + t;
        int b = offs[node], e = ends[node];
        float pp = 0.f;
        for (int j = b + c; j < e; j += 64) {
            uint32_t r = pairs[j];
            pp += __uint_as_float((r >> 17) << 16) * x[r & 0x1ffffu];
        }
        for (int o = 32; o > 0; o >>= 1) pp += __shfl_down(pp, o, 64);
        agg[t] = __shfl(pp, 0, 64);
    }
    float wr = Wrel0[c], br = brel0[c], wo = Wroot0[c];
    #pragma unroll
    for (int t = 0; t < 4; t++) {
        int node = blk16 + w * 4 + t;
        float v = agg[t] * wr + br + x[node] * wo;
        v = v > 0.f ? v : 0.f;
        uint32_t hb = rne_bf16(v);
        uint32_t pn = (uint32_t)__shfl_xor((int)hb, 1, 64);
        if (!(c & 1)) sH[(w * 4 + t) * 36 + (c >> 1)] = hb | (pn << 16);
    }
    __syncthreads();
    mfma_epilogue(c, w, sH, WgH, WgL, WrH, WrL, brel, sG, sR);
    __syncthreads();
    epilogue_writeout((int)threadIdx.x, blk16, sG, sR, Gout, Rout);
}

// transpose-read, byte-addressed: column = addr bits[6:3], subtile = the
// 128B-aligned base; lane reads bytes (addr&~127) + ((addr>>3)&15)*2 + 32*j
#define TRR(dst, base, off) \
    asm volatile("ds_read_b64_tr_b16 %0, %1 offset:" #off \
                 : "=v"(dst) : "v"(base))

// Fused aggregation + pre-transform: 16 nodes per 1-wave workgroup, MFMA
// consume, TRUE cross-iteration depth-1 pipeline with double-buffered
// 16KB stage and counted vmcnt spanning the loop back-edge.
template <bool LAST>
__global__ __launch_bounds__(64, 4) void k_aggfused(
        const int* __restrict__ offs, const int* __restrict__ ends,
        const uint32_t* __restrict__ pairs,
        const uint16_t* __restrict__ Gb, const uint16_t* __restrict__ Rb,
        const uint16_t* __restrict__ WgH, const uint16_t* __restrict__ WgL,
        const uint16_t* __restrict__ WrH, const uint16_t* __restrict__ WrL,
        const float* __restrict__ brel,
        uint16_t* __restrict__ Gout, uint16_t* __restrict__ Rout,
        const float* __restrict__ WrelL, const float* __restrict__ WrootL,
        float* __restrict__ sarr, float* __restrict__ rarr) {
    // 16KB: two 8KB stage buffers (each: chunkA 4KB + chunkB 4KB);
    // epilogue overlays buffer 0 with sH(2304B)+sG(2176B)+sR(2176B).
    __shared__ __align__(128) char smem[16384];
    int c = threadIdx.x;                  // 0..63
    int n0 = blockIdx.x * 16;             // wave owns nodes [n0, n0+16)

    // per-lane node bounds (lane's node = n0 + (c & 15); clamped at NN)
    int myNode = n0 + (c & 15);
    int nodeOK = myNode < NN;
    int nclamp = nodeOK ? myNode : NN - 1;
    int blo = offs[nclamp];
    int bhi = nodeOK ? ends[nclamp] : blo;
    uint32_t wid = (uint32_t)(bhi - blo);
    int start  = __builtin_amdgcn_readlane(blo, 0);
    int finish = __builtin_amdgcn_readlane(bhi, 15);

    int kq = (c >> 4) * 8;                // MFMA k-base for this quad
    // staging permutation (unchanged)
    int eprm  = ((c >> 5) << 2) | ((c >> 1) & 3);
    int lbyte = ((c >> 3) & 3) * 32 + (c & 1) * 16;
    uint32_t stgOff = (uint32_t)(uintptr_t)
        (__attribute__((address_space(3))) char*)smem;
    uint32_t trb0 = stgOff + ((uint32_t)(c >> 4) << 10)
                          + ((uint32_t)(c & 15) << 3);

    // C-init: direct Rb loads. acc16[nb][t] = C[node (c>>4)*4+t][nb*16+(c&15)]
    f32x4 acc16[4];
    #pragma unroll
    for (int nb = 0; nb < 4; nb++) {
        #pragma unroll
        for (int t = 0; t < 4; t++) {
            int node = n0 + (c >> 4) * 4 + t;
            int ncl = node < NN ? node : NN - 1;
            uint32_t rv = (uint32_t)Rb[ncl * 64 + nb * 16 + (c & 15)];
            acc16[nb][t] = __uint_as_float(rv << 16);
        }
    }

    const char* gbase = (const char*)Gb;

    // issue helper: 8 gld_lds (chunk A edges 0-31, chunk B edges 32-63)
    // from pairs word pp into stage buffer s (0/1).
    auto ISSUE8 = [&](uint32_t pp, int s) {
        char* dst = smem + (s ? 8192 : 0);
        #pragma unroll
        for (int i = 0; i < 4; i++) {
            uint32_t r = (uint32_t)__builtin_amdgcn_ds_bpermute(
                (eprm + i * 8) * 4, (int)pp);
            uint32_t voff = ((r & 0x1ffffu) << 7) + (uint32_t)lbyte;
            __builtin_amdgcn_global_load_lds(
                (const __attribute__((address_space(1))) void*)(gbase + voff),
                (__attribute__((address_space(3))) void*)(dst + i * 1024),
                16, 0, 0);
        }
        #pragma unroll
        for (int i = 0; i < 4; i++) {
            uint32_t r = (uint32_t)__builtin_amdgcn_ds_bpermute(
                (32 + eprm + i * 8) * 4, (int)pp);
            uint32_t voff = ((r & 0x1ffffu) << 7) + (uint32_t)lbyte;
            __builtin_amdgcn_global_load_lds(
                (const __attribute__((address_space(1))) void*)(gbase + voff),
                (__attribute__((address_space(3))) void*)(dst + 4096 + i * 1024),
                16, 0, 0);
        }
    };

    // consume helper: tr-read buffer s, 8 MFMAs with fragments afA/afB.
    auto CONSUME = [&](int s, bf16x8 afA, bf16x8 afB) {
        uint32_t ta = trb0 + (s ? 8192u : 0u);
        uint32_t tb = ta + 4096u;
        u32x2 a0, a1, a2, a3, a4, a5, a6, a7;
        TRR(a0, ta, 0);   TRR(a1, ta, 512);
        TRR(a2, ta, 128); TRR(a3, ta, 640);
        TRR(a4, ta, 256); TRR(a5, ta, 768);
        TRR(a6, ta, 384); TRR(a7, ta, 896);
        u32x2 b0, b1, b2, b3, b4, b5, b6, b7;
        TRR(b0, tb, 0);   TRR(b1, tb, 512);
        TRR(b2, tb, 128); TRR(b3, tb, 640);
        TRR(b4, tb, 256); TRR(b5, tb, 768);
        TRR(b6, tb, 384); TRR(b7, tb, 896);
        asm volatile("s_waitcnt lgkmcnt(0)" ::: "memory");
        __builtin_amdgcn_sched_barrier(0);
        u32x4 v0 = { a0.x, a0.y, a1.x, a1.y };
        acc16[0] = __builtin_amdgcn_mfma_f32_16x16x32_bf16(
            afA, __builtin_bit_cast(bf16x8, v0), acc16[0], 0, 0, 0);
        u32x4 v1 = { a2.x, a2.y, a3.x, a3.y };
        acc16[1] = __builtin_amdgcn_mfma_f32_16x16x32_bf16(
            afA, __builtin_bit_cast(bf16x8, v1), acc16[1], 0, 0, 0);
        u32x4 v2 = { a4.x, a4.y, a5.x, a5.y };
        acc16[2] = __builtin_amdgcn_mfma_f32_16x16x32_bf16(
            afA, __builtin_bit_cast(bf16x8, v2), acc16[2], 0, 0, 0);
        u32x4 v3 = { a6.x, a6.y, a7.x, a7.y };
        acc16[3] = __builtin_amdgcn_mfma_f32_16x16x32_bf16(
            afA, __builtin_bit_cast(bf16x8, v3), acc16[3], 0, 0, 0);
        u32x4 w0 = { b0.x, b0.y, b1.x, b1.y };
        acc16[0] = __builtin_amdgcn_mfma_f32_16x16x32_bf16(
            afB, __builtin_bit_cast(bf16x8, w0), acc16[0], 0, 0, 0);
        u32x4 w1 = { b2.x, b2.y, b3.x, b3.y };
        acc16[1] = __builtin_amdgcn_mfma_f32_16x16x32_bf16(
            afB, __builtin_bit_cast(bf16x8, w1), acc16[1], 0, 0, 0);
        u32x4 w2 = { b4.x, b4.y, b5.x, b5.y };
        acc16[2] = __builtin_amdgcn_mfma_f32_16x16x32_bf16(
            afB, __builtin_bit_cast(bf16x8, w2), acc16[2], 0, 0, 0);
        u32x4 w3 = { b6.x, b6.y, b7.x, b7.y };
        acc16[3] = __builtin_amdgcn_mfma_f32_16x16x32_bf16(
            afB, __builtin_bit_cast(bf16x8, w3), acc16[3], 0, 0, 0);
    };

    // build masked A fragments for super-chunk at cb from pairs word pp
    auto AFRAGS = [&](uint32_t pp, int cb, bf16x8& afA, bf16x8& afB) {
        uint32_t mA[8], mB[8];
        int dbA = cb + kq - blo;
        int dbB = cb + 32 + kq - blo;
        #pragma unroll
        for (int q = 0; q < 8; q++) {
            uint32_t rq = (uint32_t)__builtin_amdgcn_ds_bpermute(
                (kq + q) * 4, (int)pp);
            mA[q] = ((uint32_t)(dbA + q) < wid) ? (rq >> 17) : 0u;
        }
        #pragma unroll
        for (int q = 0; q < 8; q++) {
            uint32_t rq = (uint32_t)__builtin_amdgcn_ds_bpermute(
                (32 + kq + q) * 4, (int)pp);
            mB[q] = ((uint32_t)(dbB + q) < wid) ? (rq >> 17) : 0u;
        }
        u32x4 aav = { mA[0] | (mA[1] << 16), mA[2] | (mA[3] << 16),
                      mA[4] | (mA[5] << 16), mA[6] | (mA[7] << 16) };
        u32x4 abv = { mB[0] | (mB[1] << 16), mB[2] | (mB[3] << 16),
                      mB[4] | (mB[5] << 16), mB[6] | (mB[7] << 16) };
        afA = __builtin_bit_cast(bf16x8, aav);
        afB = __builtin_bit_cast(bf16x8, abv);
    };

    // ---- prologue: prime the pipeline ----
    int j0 = start + c; if (j0 > PMAX - 1) j0 = PMAX - 1;
    uint32_t praw = pairs[j0];
    asm volatile("s_waitcnt vmcnt(0)" ::: "memory");   // clean ledger
    uint32_t p = (start + c < finish) ? praw : 0;
    int j1 = start + 64 + c; if (j1 > PMAX - 1) j1 = PMAX - 1;
    uint32_t pnext = pairs[j1];          // vmem slot 1 (oldest)
    ISSUE8(p, 0);                        // vmem slots 2-9
    int sel = 0;

    for (int cb = start; cb < finish; cb += 64) {
        bf16x8 afA, afB;
        uint32_t pn = 0, pnext2 = 0;
        if (cb + 64 < finish) {          // wave-uniform
            // pairs_{i+1} ready (issued a full iteration ago)
            asm volatile("s_waitcnt vmcnt(8)" ::: "memory");
            pn = (cb + 64 + c < finish) ? pnext : 0;
            int j2 = cb + 128 + c; if (j2 > PMAX - 1) j2 = PMAX - 1;
            pnext2 = pairs[j2];          // issue pairs_{i+2}
            ISSUE8(pn, sel ^ 1);         // issue iter i+1's gathers
            AFRAGS(p, cb, afA, afB);     // masks under flight
            // iter i's gathers (issued last iteration) complete
            asm volatile("s_waitcnt vmcnt(9)" ::: "memory");
        } else {
            AFRAGS(p, cb, afA, afB);
            asm volatile("s_waitcnt vmcnt(0)" ::: "memory");
        }
        CONSUME(sel, afA, afB);
        p = pn; pnext = pnext2; sel ^= 1;
    }
    // drain any in-flight gathers before overlaying the stage with sH
    asm volatile("s_waitcnt vmcnt(0)" ::: "memory");

    if (!LAST) {
        // pack relu(C) -> sH (overlay stage buffer 0)
        uint32_t* sHw = (uint32_t*)smem;
        #pragma unroll
        for (int t = 0; t < 4; t++) {
            #pragma unroll
            for (int nb = 0; nb < 4; nb++) {
                float v = acc16[nb][t];
                v = v > 0.f ? v : 0.f;
                uint32_t hb = rne_bf16(v);
                uint32_t pn2 = (uint32_t)__shfl_xor((int)hb, 1, 64);
                if (!(c & 1))
                    sHw[((c >> 4) * 4 + t) * 36 + nb * 8 + ((c & 15) >> 1)]
                        = hb | (pn2 << 16);
            }
        }
        asm volatile("s_waitcnt lgkmcnt(0)" ::: "memory");
        __builtin_amdgcn_sched_barrier(0);
        // wave-private epilogue: G = h x Wrel (hi/lo), R = h x Wroot + brel
        uint16_t* sGw = (uint16_t*)(smem + 2304);
        uint16_t* sRw = (uint16_t*)(smem + 2304 + 2176);
        int row = c & 15;
        int quad = c >> 4;
        int kb = quad * 8;
        bf16x8 ah0 = *(const bf16x8*)&sHw[row * 36 + quad * 4];
        bf16x8 ah1 = *(const bf16x8*)&sHw[row * 36 + 16 + quad * 4];
        #pragma unroll
        for (int ob = 0; ob < 4; ob++) {
            int oc = ob * 16 + row;
            {
                bf16x8 bh0 = *(const bf16x8*)&WgH[oc * 64 + kb];
                bf16x8 bh1 = *(const bf16x8*)&WgH[oc * 64 + 32 + kb];
                bf16x8 bl0 = *(const bf16x8*)&WgL[oc * 64 + kb];
                bf16x8 bl1 = *(const bf16x8*)&WgL[oc * 64 + 32 + kb];
                f32x4 acc = {0.f, 0.f, 0.f, 0.f};
                acc = __builtin_amdgcn_mfma_f32_16x16x32_bf16(ah0, bh0, acc, 0, 0, 0);
                acc = __builtin_amdgcn_mfma_f32_16x16x32_bf16(ah1, bh1, acc, 0, 0, 0);
                acc = __builtin_amdgcn_mfma_f32_16x16x32_bf16(ah0, bl0, acc, 0, 0, 0);
                acc = __builtin_amdgcn_mfma_f32_16x16x32_bf16(ah1, bl1, acc, 0, 0, 0);
                #pragma unroll
                for (int r = 0; r < 4; r++)
                    sGw[(quad * 4 + r) * 68 + oc] = (uint16_t)rne_bf16(acc[r]);
            }
            {
                bf16x8 bh0 = *(const bf16x8*)&WrH[oc * 64 + kb];
                bf16x8 bh1 = *(const bf16x8*)&WrH[oc * 64 + 32 + kb];
                bf16x8 bl0 = *(const bf16x8*)&WrL[oc * 64 + kb];
                bf16x8 bl1 = *(const bf16x8*)&WrL[oc * 64 + 32 + kb];
                float bias = brel[oc];
                f32x4 acc = {bias, bias, bias, bias};
                acc = __builtin_amdgcn_mfma_f32_16x16x32_bf16(ah0, bh0, acc, 0, 0, 0);
                acc = __builtin_amdgcn_mfma_f32_16x16x32_bf16(ah1, bh1, acc, 0, 0, 0);
                acc = __builtin_amdgcn_mfma_f32_16x16x32_bf16(ah0, bl0, acc, 0, 0, 0);
                acc = __builtin_amdgcn_mfma_f32_16x16x32_bf16(ah1, bl1, acc, 0, 0, 0);
                #pragma unroll
                for (int r = 0; r < 4; r++)
                    sRw[(quad * 4 + r) * 68 + oc] = (uint16_t)rne_bf16(acc[r]);
            }
        }
        asm volatile("s_waitcnt lgkmcnt(0)" ::: "memory");
        __builtin_amdgcn_sched_barrier(0);
        // write-out: 16 nodes x 32 dwords, 64 lanes -> 8 iters
        const uint32_t* sGd = (const uint32_t*)sGw;
        const uint32_t* sRd = (const uint32_t*)sRw;
        uint32_t* Gd = (uint32_t*)Gout;
        uint32_t* Rd = (uint32_t*)Rout;
        #pragma unroll
        for (int it = 0; it < 8; it++) {
            int idx = it * 64 + c;
            int nd = idx >> 5, col = idx & 31;
            int node = n0 + nd;
            if (node < NN) {
                Gd[node * 32 + col] = sGd[nd * 34 + col];
                Rd[node * 32 + col] = sRd[nd * 34 + col];
            }
        }
    } else {
        float wl[4], wo[4];
        #pragma unroll
        for (int nb = 0; nb < 4; nb++) {
            wl[nb] = WrelL[nb * 16 + (c & 15)];
            wo[nb] = WrootL[nb * 16 + (c & 15)];
        }
        #pragma unroll
        for (int t = 0; t < 4; t++) {
            float pa = 0.f, pr = 0.f;
            #pragma unroll
            for (int nb = 0; nb < 4; nb++) {
                float v = acc16[nb][t];
                v = v > 0.f ? v : 0.f;
                pa += v * wl[nb];
                pr += v * wo[nb];
            }
            #pragma unroll
            for (int o = 8; o > 0; o >>= 1) {
                pa += __shfl_down(pa, o, 64);
                pr += __shfl_down(pr, o, 64);
            }
            int node = n0 + (c >> 4) * 4 + t;
            if (!(c & 15) && node < NN) { sarr[node] = pa; rarr[node] = pr; }
        }
    }
}

// final edge pass: wave-per-4-nodes edge-parallel gather + shfl reduce
__global__ __launch_bounds__(256) void k_last(
        const int* __restrict__ offs, const int* __restrict__ ends,
        const uint32_t* __restrict__ pairs,
        const float* __restrict__ sarr, const float* __restrict__ rarr,
        const float* __restrict__ brelL, float* __restrict__ out) {
    int c = threadIdx.x & 63;
    int w = threadIdx.x >> 6;
    int blk16 = blockIdx.x * 16;
    float b0 = brelL[0];
    #pragma unroll
    for (int t = 0; t < 4; t++) {
        int node = blk16 + w * 4 + t;
        int b = offs[node], e = ends[node];
        float pp = 0.f;
        for (int j = b + c; j < e; j += 64) {
            uint32_t r = pairs[j];
            pp += __uint_as_float((r >> 17) << 16) * sarr[r & 0x1ffffu];
        }
        #pragma unroll
        for (int o = 32; o > 0; o >>= 1) pp += __shfl_down(pp, o, 64);
        if (c == 0) out[node] = pp + rarr[node] + b0;
    }
}

extern "C" void kernel_launch(void* const* d_in, const int* in_sizes, int n_in,
                              void* d_out, int out_size, void* d_ws, size_t ws_size,
                              hipStream_t stream) {
    const float* x        = (const float*)d_in[0];
    const int*   ei       = (const int*)d_in[1];
    const float* ew       = (const float*)d_in[2];
    const float* Wrel0    = (const float*)d_in[3];
    const float* brel0    = (const float*)d_in[4];
    const float* Wroot0   = (const float*)d_in[5];
    const float* Wrel_mid = (const float*)d_in[6];
    const float* brel_mid = (const float*)d_in[7];
    const float* Wroot_mid= (const float*)d_in[8];
    const float* WrelL    = (const float*)d_in[9];
    const float* brelL    = (const float*)d_in[10];
    const float* WrootL   = (const float*)d_in[11];
    float* out = (float*)d_out;

    const int* src  = ei;
    const int* dstp = ei + NE;

    char* w = (char*)d_ws;
    size_t o = 0;
    auto alloc = [&](size_t b) -> void* {
        void* r = (void*)(w + o);
        o += (b + 255) & ~(size_t)255;
        return r;
    };
    int*      offs  = (int*)alloc((size_t)NN * 4);
    int*      ends  = (int*)alloc((size_t)NN * 4);
    int*      bcur  = (int*)alloc((size_t)NBKT * 4);
    uint16_t* WgH   = (uint16_t*)alloc((size_t)3 * 4096 * 2);
    uint16_t* WgL   = (uint16_t*)alloc((size_t)3 * 4096 * 2);
    uint16_t* WrH   = (uint16_t*)alloc((size_t)3 * 4096 * 2);
    uint16_t* WrL   = (uint16_t*)alloc((size_t)3 * 4096 * 2);
    float*    sarr  = (float*)alloc((size_t)NN * 4);
    float*    rarr  = (float*)alloc((size_t)NN * 4);
    uint32_t* pairs = (uint32_t*)alloc((size_t)NBKT * CAP * 4);  // 12.8 MB padded
    uint16_t* GbA   = (uint16_t*)alloc((size_t)NN * HID * 2);    // 12.8 MB
    uint16_t* RbA   = (uint16_t*)alloc((size_t)NN * HID * 2);
    uint16_t* GbB   = (uint16_t*)alloc((size_t)NN * HID * 2);    // GbB/RbB contiguous
    uint16_t* RbB   = (uint16_t*)alloc((size_t)NN * HID * 2);
    (void)RbB;
    // bpairs (NBKT*CAP*8B = 25.6MB) aliases GbB+RbB (contiguous; dead before
    // mid layer 1 writes set B)
    int2*  bpairs = (int2*)GbB;

    // weight split + bucket cursor init (one launch)
    k_wsplit<<<(3 * 4096 + 255) / 256, 256, 0, stream>>>(
        Wrel_mid, Wroot_mid, WgH, WgL, WrH, WrL, bcur);

    // CSR build (padded buckets)
    k_bpart<<<NTILE, 256, 0, stream>>>(src, dstp, ew, bcur, bpairs);
    k_bcsr<<<NBKT, 256, 0, stream>>>(bcur, bpairs, offs, ends, pairs);

    // layer 0 (agg + transform + pre) -> G1,R1 (set A)
    k_l0pre<<<NN / 16, 256, 0, stream>>>(
        offs, ends, pairs, x, Wrel0, brel0, Wroot0,
        WgH, WgL, WrH, WrL, brel_mid, GbA, RbA);

    int nagg = (NN + 15) / 16;   // 6250 one-wave blocks, 16 nodes each
    // mid layer 1: consume set A, produce set B (weights index 1)
    k_aggfused<false><<<nagg, 64, 0, stream>>>(
        offs, ends, pairs, GbA, RbA,
        WgH + 4096, WgL + 4096, WrH + 4096, WrL + 4096, brel_mid + HID,
        GbB, RbB, WrelL, WrootL, sarr, rarr);
    // mid layer 2: consume set B, produce set A (weights index 2)
    k_aggfused<false><<<nagg, 64, 0, stream>>>(
        offs, ends, pairs, GbB, RbB,
        WgH + 2 * 4096, WgL + 2 * 4096, WrH + 2 * 4096, WrL + 2 * 4096,
        brel_mid + 2 * HID, GbA, RbA, WrelL, WrootL, sarr, rarr);
    // mid layer 3 (LAST): consume set A, produce s/r scalars
    k_aggfused<true><<<nagg, 64, 0, stream>>>(
        offs, ends, pairs, GbA, RbA,
        WgH, WgL, WrH, WrL, brel_mid,
        GbB, RbB, WrelL, WrootL, sarr, rarr);

    // final edge pass on scalars (16 nodes/block -> NN/16 blocks)
    k_last<<<NN / 16, 256, 0, stream>>>(offs, ends, pairs, sarr, rarr, brelL, out);
}

// Round 11
// 288.491 us; speedup vs baseline: 1.1001x; 1.1001x over previous
//
#include <hip/hip_runtime.h>
#include <stdint.h>

// GraphConv x5 on MI355X — round 30.
// vs round 29 (317us; pipeline REGRESSED 49.7->58.4, occupancy 19%):
// latency exposure falsified — all 6 schedule variants pin beyond-L2
// traffic at ~112MB and ~2.3TB/s => traffic-bound. Fix by LINEARITY:
// Wrel.(sum w.h) == sum w.(Wrel.h), so layers store ONLY h (12.8MB, not
// G+R 25.6MB). Mid layer: gather h rows (unchanged 128B gather, r28's
// proven schedule, C-init=0, Rb read GONE), epilogue computes h_next =
// relu(Wrel.agg + Wroot.h_self + brel) — same 32 MFMAs, h_self = two
// direct 16B loads (L2-hot). Per-layer traffic 112->~86MB. l0pre loses
// its whole MFMA epilogue (writes only h1). LAST runs epilogue + width-16
// shfl dots. Weights: layer i uses its own W_i.

#define NN 100000
#define NE 1600000
#define HID 64
#define NBKT 391            // ceil(NN/256), bucket = dst >> 8
#define CAP 8192            // padded bucket capacity (mean 4092, +64 sigma)
#define PMAX (NBKT * CAP)
#define TILE 4096
#define EPT 16              // TILE / 256
#define NTILE ((NE + TILE - 1) / TILE)   // 391

typedef __attribute__((ext_vector_type(8))) short bf16x8;
typedef __attribute__((ext_vector_type(4))) float f32x4;
typedef __attribute__((ext_vector_type(2))) unsigned int u32x2;
typedef __attribute__((ext_vector_type(4))) unsigned int u32x4;

__device__ __forceinline__ uint32_t rne_bf16(float v) {
    uint32_t u = __float_as_uint(v);
    return (u + 0x7fffu + ((u >> 16) & 1u)) >> 16;
}

// ---------------- CSR build ----------------

// tile-local LDS counting sort + coalesced segment write-out
__global__ __launch_bounds__(256) void k_bpart(const int* __restrict__ src,
                                               const int* __restrict__ dst,
                                               const float* __restrict__ w,
                                               int* __restrict__ bcur,
                                               int2* __restrict__ bpairs) {
    __shared__ int  hcnt[NBKT];      // count, then cursor
    __shared__ int  hoff[NBKT];      // local exclusive offset
    __shared__ int  hadj[NBKT];      // global base - local offset
    __shared__ int  sc0[512];
    __shared__ int  sc1[512];
    __shared__ int2 sT[TILE];        // 32 KB staged tile (bucket-sorted)
    __shared__ int  sAdj[TILE];      // 16 KB per-slot global adjust
    int tile0 = blockIdx.x * TILE;
    int t = threadIdx.x;
    for (int i = t; i < NBKT; i += 256) hcnt[i] = 0;
    __syncthreads();

    int   pk[EPT];
    int   bk[EPT];
    float wv[EPT];
    #pragma unroll
    for (int k = 0; k < EPT; k++) {
        int e = tile0 + t + k * 256;
        if (e < NE) {
            int d = dst[e];
            int b = d >> 8;
            pk[k] = (src[e] << 8) | (d & 255);
            wv[k] = w[e];
            bk[k] = b;
            atomicAdd(&hcnt[b], 1);
        } else {
            bk[k] = -1;
        }
    }
    __syncthreads();

    // inclusive scan of hcnt over 512 (padded) with ping-pong buffers
    sc0[t]       = (t < NBKT) ? hcnt[t] : 0;
    sc0[t + 256] = (t + 256 < NBKT) ? hcnt[t + 256] : 0;
    __syncthreads();
    int* cur = sc0;
    int* oth = sc1;
    for (int off = 1; off < 512; off <<= 1) {
        int v0 = cur[t]       + ((t       >= off) ? cur[t - off]       : 0);
        int v1 = cur[t + 256] + ((t + 256 >= off) ? cur[t + 256 - off] : 0);
        oth[t] = v0;
        oth[t + 256] = v1;
        __syncthreads();
        int* tmp = cur; cur = oth; oth = tmp;
    }
    for (int i = t; i < NBKT; i += 256) {
        int c = hcnt[i];
        int excl = cur[i] - c;
        hoff[i] = excl;
        int gbase = c ? atomicAdd(&bcur[i], c) : 0;
        hadj[i] = gbase - excl;
        hcnt[i] = 0;                 // reuse as local cursor
    }
    __syncthreads();

    // scatter into LDS (bucket-sorted order)
    #pragma unroll
    for (int k = 0; k < EPT; k++) {
        if (bk[k] >= 0) {
            int b = bk[k];
            int pos = hoff[b] + atomicAdd(&hcnt[b], 1);
            sT[pos] = make_int2(pk[k], __float_as_int(wv[k]));
            sAdj[pos] = hadj[b];
        }
    }
    __syncthreads();

    // linear write-out: consecutive slots in a bucket run -> consecutive
    // global addresses (coalesced bursts)
    int n = NE - tile0; if (n > TILE) n = TILE;
    for (int j = t; j < n; j += 256)
        bpairs[sAdj[j] + j] = sT[j];
}

// one block per bucket: stage bucket in LDS, then LDS counting sort.
__global__ __launch_bounds__(256) void k_bcsr(const int* __restrict__ bcur,
                                              const int2* __restrict__ bpairs,
                                              int* __restrict__ offs,
                                              int* __restrict__ ends,
                                              uint32_t* __restrict__ pairs) {
    __shared__ int2 sE[CAP];        // 64 KB bucket stage
    __shared__ int cnt[256];
    __shared__ int scn[256];
    __shared__ int cur[256];
    int k = blockIdx.x, t = threadIdx.x;
    int base = k * CAP;
    int scnt = bcur[k] - base;
    cnt[t] = 0;
    __syncthreads();
    for (int j = t; j < scnt; j += 256) {
        int2 q = bpairs[base + j];
        sE[j] = q;
        atomicAdd(&cnt[q.x & 255], 1);
    }
    __syncthreads();
    int v = cnt[t], acc = v;
    scn[t] = v;
    __syncthreads();
    for (int off = 1; off < 256; off <<= 1) {
        int u = (t >= off) ? scn[t - off] : 0;
        __syncthreads();
        acc += u;
        scn[t] = acc;
        __syncthreads();
    }
    int excl = acc - v;
    cur[t] = excl;
    int d = (k << 8) + t;
    if (d < NN) {
        offs[d] = base + excl;
        ends[d] = base + excl + v;
    }
    __syncthreads();
    for (int j = t; j < scnt; j += 256) {
        int2 q = sE[j];
        int pos = base + atomicAdd(&cur[q.x & 255], 1);
        uint32_t wb = rne_bf16(__int_as_float(q.y)) & 0x7fffu;   // w >= 0
        pairs[pos] = (wb << 17) | (uint32_t)(q.x >> 8);
    }
}

// ---------------- weight hi/lo split (+ bucket cursor init) ----------------

__global__ __launch_bounds__(256) void k_wsplit(const float* __restrict__ Wrel_mid,
                                                const float* __restrict__ Wroot_mid,
                                                uint16_t* __restrict__ WgH,
                                                uint16_t* __restrict__ WgL,
                                                uint16_t* __restrict__ WrH,
                                                uint16_t* __restrict__ WrL,
                                                int* __restrict__ bcur) {
    int i = blockIdx.x * blockDim.x + threadIdx.x;
    if (i < NBKT) bcur[i] = i * CAP;
    if (i >= 3 * 4096) return;
    float a = Wrel_mid[i];
    uint32_t ah = rne_bf16(a);
    float al = a - __uint_as_float(ah << 16);
    WgH[i] = (uint16_t)ah;
    WgL[i] = (uint16_t)rne_bf16(al);
    float b = Wroot_mid[i];
    uint32_t bh = rne_bf16(b);
    float bl = b - __uint_as_float(bh << 16);
    WrH[i] = (uint16_t)bh;
    WrL[i] = (uint16_t)rne_bf16(bl);
}

// ---------------- layers ----------------

// layer 0: edge-parallel aggregation (4 nodes/wave, shfl reduce), then
// h1 = relu(agg*Wrel0 + brel0 + x*Wroot0) written DIRECTLY as bf16 rows.
__global__ __launch_bounds__(256) void k_l0pre(
        const int* __restrict__ offs, const int* __restrict__ ends,
        const uint32_t* __restrict__ pairs, const float* __restrict__ x,
        const float* __restrict__ Wrel0, const float* __restrict__ brel0,
        const float* __restrict__ Wroot0,
        uint16_t* __restrict__ Hout) {
    int c = threadIdx.x & 63;
    int w = threadIdx.x >> 6;
    int blk16 = blockIdx.x * 16;
    float agg[4];
    #pragma unroll
    for (int t = 0; t < 4; t++) {
        int node = blk16 + w * 4 + t;
        int b = offs[node], e = ends[node];
        float pp = 0.f;
        for (int j = b + c; j < e; j += 64) {
            uint32_t r = pairs[j];
            pp += __uint_as_float((r >> 17) << 16) * x[r & 0x1ffffu];
        }
        for (int o = 32; o > 0; o >>= 1) pp += __shfl_down(pp, o, 64);
        agg[t] = __shfl(pp, 0, 64);
    }
    float wr = Wrel0[c], br = brel0[c], wo = Wroot0[c];
    uint32_t* Hd = (uint32_t*)Hout;
    #pragma unroll
    for (int t = 0; t < 4; t++) {
        int node = blk16 + w * 4 + t;
        float v = agg[t] * wr + br + x[node] * wo;
        v = v > 0.f ? v : 0.f;
        uint32_t hb = rne_bf16(v);
        uint32_t pn = (uint32_t)__shfl_xor((int)hb, 1, 64);
        if (!(c & 1)) Hd[node * 32 + (c >> 1)] = hb | (pn << 16);
    }
}

// transpose-read, byte-addressed: column = addr bits[6:3], subtile = the
// 128B-aligned base; lane reads bytes (addr&~127) + ((addr>>3)&15)*2 + 32*j
#define TRRA(dst, off) \
    asm volatile("ds_read_b64_tr_b16 %0, %1 offset:" #off \
                 : "=v"(dst) : "v"(trbA))
#define TRRB(dst, off) \
    asm volatile("ds_read_b64_tr_b16 %0, %1 offset:" #off \
                 : "=v"(dst) : "v"(trbB))

// Mid layer: gather h rows (r28 schedule), agg via MFMA (C-init 0),
// epilogue h_next = relu(Wrel.agg + Wroot.h_self + brel). LAST: epilogue
// then width-16 shfl dots with WrelL/WrootL -> sarr/rarr.
template <bool LAST>
__global__ __launch_bounds__(64, 5) void k_aggfused(
        const int* __restrict__ offs, const int* __restrict__ ends,
        const uint32_t* __restrict__ pairs,
        const uint16_t* __restrict__ Hb,
        const uint16_t* __restrict__ WgH, const uint16_t* __restrict__ WgL,
        const uint16_t* __restrict__ WrH, const uint16_t* __restrict__ WrL,
        const float* __restrict__ brel,
        uint16_t* __restrict__ Hout,
        const float* __restrict__ WrelL, const float* __restrict__ WrootL,
        float* __restrict__ sarr, float* __restrict__ rarr) {
    // 8KB gather stage (2x4KB chunk bufs); epilogue overlays with
    // sH(agg, 2304B) + sO(2176B).
    __shared__ __align__(128) char smem[8192];
    int c = threadIdx.x;                  // 0..63
    int n0 = blockIdx.x * 16;             // wave owns nodes [n0, n0+16)
    // NN % 16 == 0 -> no node clamping anywhere.

    int myNode = n0 + (c & 15);
    int blo = offs[myNode];
    int bhi = ends[myNode];
    uint32_t wid = (uint32_t)(bhi - blo);
    int start  = __builtin_amdgcn_readlane(blo, 0);
    int finish = __builtin_amdgcn_readlane(bhi, 15);

    int kq = (c >> 4) * 8;                // MFMA k-base for this quad
    int eprm  = ((c >> 5) << 2) | ((c >> 1) & 3);
    int lbyte = ((c >> 3) & 3) * 32 + (c & 1) * 16;
    char* stg = smem;                     // chunk A: stg, chunk B: +4096
    uint32_t stgOff = (uint32_t)(uintptr_t)
        (__attribute__((address_space(3))) char*)stg;
    uint32_t trbA = stgOff + ((uint32_t)(c >> 4) << 10)
                          + ((uint32_t)(c & 15) << 3);
    uint32_t trbB = trbA + 4096;

    f32x4 acc16[4];
    #pragma unroll
    for (int nb = 0; nb < 4; nb++) acc16[nb] = f32x4{0.f, 0.f, 0.f, 0.f};

    const char* gbase = (const char*)Hb;
    int j0 = start + c; if (j0 > PMAX - 1) j0 = PMAX - 1;
    uint32_t praw = pairs[j0];
    uint32_t p = (start + c < finish) ? praw : 0;

    for (int cb = start; cb < finish; cb += 64) {
        int jn = cb + 64 + c; if (jn > PMAX - 1) jn = PMAX - 1;
        uint32_t pr2 = pairs[jn];                               // vmem 1
        #pragma unroll
        for (int i = 0; i < 4; i++) {                           // vmem 2-5
            uint32_t r = (uint32_t)__builtin_amdgcn_ds_bpermute(
                (eprm + i * 8) * 4, (int)p);
            uint32_t voff = ((r & 0x1ffffu) << 7) + (uint32_t)lbyte;
            __builtin_amdgcn_global_load_lds(
                (const __attribute__((address_space(1))) void*)(gbase + voff),
                (__attribute__((address_space(3))) void*)(stg + i * 1024),
                16, 0, 0);
        }
        #pragma unroll
        for (int i = 0; i < 4; i++) {                           // vmem 6-9
            uint32_t r = (uint32_t)__builtin_amdgcn_ds_bpermute(
                (32 + eprm + i * 8) * 4, (int)p);
            uint32_t voff = ((r & 0x1ffffu) << 7) + (uint32_t)lbyte;
            __builtin_amdgcn_global_load_lds(
                (const __attribute__((address_space(1))) void*)(gbase + voff),
                (__attribute__((address_space(3))) void*)(stg + 4096 + i * 1024),
                16, 0, 0);
        }
        uint32_t mA[8], mB[8];
        int dbA = cb + kq - blo;
        int dbB = cb + 32 + kq - blo;
        #pragma unroll
        for (int q = 0; q < 8; q++) {
            uint32_t rq = (uint32_t)__builtin_amdgcn_ds_bpermute(
                (kq + q) * 4, (int)p);
            mA[q] = ((uint32_t)(dbA + q) < wid) ? (rq >> 17) : 0u;
        }
        #pragma unroll
        for (int q = 0; q < 8; q++) {
            uint32_t rq = (uint32_t)__builtin_amdgcn_ds_bpermute(
                (32 + kq + q) * 4, (int)p);
            mB[q] = ((uint32_t)(dbB + q) < wid) ? (rq >> 17) : 0u;
        }
        u32x4 aav = { mA[0] | (mA[1] << 16), mA[2] | (mA[3] << 16),
                      mA[4] | (mA[5] << 16), mA[6] | (mA[7] << 16) };
        u32x4 abv = { mB[0] | (mB[1] << 16), mB[2] | (mB[3] << 16),
                      mB[4] | (mB[5] << 16), mB[6] | (mB[7] << 16) };
        bf16x8 afA = __builtin_bit_cast(bf16x8, aav);
        bf16x8 afB = __builtin_bit_cast(bf16x8, abv);
        asm volatile("s_waitcnt vmcnt(4)" ::: "memory");
        {
            u32x2 tb0, tb1, tb2, tb3, tb4, tb5, tb6, tb7;
            TRRA(tb0, 0);   TRRA(tb1, 512);
            TRRA(tb2, 128); TRRA(tb3, 640);
            TRRA(tb4, 256); TRRA(tb5, 768);
            TRRA(tb6, 384); TRRA(tb7, 896);
            asm volatile("s_waitcnt lgkmcnt(0)" ::: "memory");
            __builtin_amdgcn_sched_barrier(0);
            u32x4 bb0 = { tb0.x, tb0.y, tb1.x, tb1.y };
            acc16[0] = __builtin_amdgcn_mfma_f32_16x16x32_bf16(
                afA, __builtin_bit_cast(bf16x8, bb0), acc16[0], 0, 0, 0);
            u32x4 bb1 = { tb2.x, tb2.y, tb3.x, tb3.y };
            acc16[1] = __builtin_amdgcn_mfma_f32_16x16x32_bf16(
                afA, __builtin_bit_cast(bf16x8, bb1), acc16[1], 0, 0, 0);
            u32x4 bb2 = { tb4.x, tb4.y, tb5.x, tb5.y };
            acc16[2] = __builtin_amdgcn_mfma_f32_16x16x32_bf16(
                afA, __builtin_bit_cast(bf16x8, bb2), acc16[2], 0, 0, 0);
            u32x4 bb3 = { tb6.x, tb6.y, tb7.x, tb7.y };
            acc16[3] = __builtin_amdgcn_mfma_f32_16x16x32_bf16(
                afA, __builtin_bit_cast(bf16x8, bb3), acc16[3], 0, 0, 0);
        }
        asm volatile("s_waitcnt vmcnt(0)" ::: "memory");
        {
            u32x2 tb0, tb1, tb2, tb3, tb4, tb5, tb6, tb7;
            TRRB(tb0, 0);   TRRB(tb1, 512);
            TRRB(tb2, 128); TRRB(tb3, 640);
            TRRB(tb4, 256); TRRB(tb5, 768);
            TRRB(tb6, 384); TRRB(tb7, 896);
            asm volatile("s_waitcnt lgkmcnt(0)" ::: "memory");
            __builtin_amdgcn_sched_barrier(0);
            u32x4 bb0 = { tb0.x, tb0.y, tb1.x, tb1.y };
            acc16[0] = __builtin_amdgcn_mfma_f32_16x16x32_bf16(
                afB, __builtin_bit_cast(bf16x8, bb0), acc16[0], 0, 0, 0);
            u32x4 bb1 = { tb2.x, tb2.y, tb3.x, tb3.y };
            acc16[1] = __builtin_amdgcn_mfma_f32_16x16x32_bf16(
                afB, __builtin_bit_cast(bf16x8, bb1), acc16[1], 0, 0, 0);
            u32x4 bb2 = { tb4.x, tb4.y, tb5.x, tb5.y };
            acc16[2] = __builtin_amdgcn_mfma_f32_16x16x32_bf16(
                afB, __builtin_bit_cast(bf16x8, bb2), acc16[2], 0, 0, 0);
            u32x4 bb3 = { tb6.x, tb6.y, tb7.x, tb7.y };
            acc16[3] = __builtin_amdgcn_mfma_f32_16x16x32_bf16(
                afB, __builtin_bit_cast(bf16x8, bb3), acc16[3], 0, 0, 0);
        }
        p = (cb + 64 + c < finish) ? pr2 : 0;
    }
    asm volatile("s_waitcnt vmcnt(0)" ::: "memory");

    // ---- shared epilogue: h' = Wrel.agg + Wroot.h_self + brel ----
    int row = c & 15;
    int quad = c >> 4;
    int kb = quad * 8;
    // h_self fragments: direct 16B loads (L2-hot; A-fragment layout)
    bf16x8 hs0 = *(const bf16x8*)&Hb[(n0 + row) * 64 + kb];
    bf16x8 hs1 = *(const bf16x8*)&Hb[(n0 + row) * 64 + 32 + kb];
    // pack agg (NO relu) -> sH, overlaying dead gather stage
    uint32_t* sHw = (uint32_t*)smem;
    #pragma unroll
    for (int t = 0; t < 4; t++) {
        #pragma unroll
        for (int nb = 0; nb < 4; nb++) {
            uint32_t hb = rne_bf16(acc16[nb][t]);
            uint32_t pn2 = (uint32_t)__shfl_xor((int)hb, 1, 64);
            if (!(c & 1))
                sHw[(quad * 4 + t) * 36 + nb * 8 + (row >> 1)]
                    = hb | (pn2 << 16);
        }
    }
    asm volatile("s_waitcnt lgkmcnt(0)" ::: "memory");
    __builtin_amdgcn_sched_barrier(0);
    bf16x8 ah0 = *(const bf16x8*)&sHw[row * 36 + quad * 4];
    bf16x8 ah1 = *(const bf16x8*)&sHw[row * 36 + 16 + quad * 4];

    if (!LAST) {
        uint16_t* sO = (uint16_t*)(smem + 2304);
        #pragma unroll
        for (int ob = 0; ob < 4; ob++) {
            int oc = ob * 16 + row;
            float bias = brel[oc];
            f32x4 acc = {bias, bias, bias, bias};
            bf16x8 gh0 = *(const bf16x8*)&WgH[oc * 64 + kb];
            bf16x8 gh1 = *(const bf16x8*)&WgH[oc * 64 + 32 + kb];
            bf16x8 gl0 = *(const bf16x8*)&WgL[oc * 64 + kb];
            bf16x8 gl1 = *(const bf16x8*)&WgL[oc * 64 + 32 + kb];
            acc = __builtin_amdgcn_mfma_f32_16x16x32_bf16(ah0, gh0, acc, 0, 0, 0);
            acc = __builtin_amdgcn_mfma_f32_16x16x32_bf16(ah1, gh1, acc, 0, 0, 0);
            acc = __builtin_amdgcn_mfma_f32_16x16x32_bf16(ah0, gl0, acc, 0, 0, 0);
            acc = __builtin_amdgcn_mfma_f32_16x16x32_bf16(ah1, gl1, acc, 0, 0, 0);
            bf16x8 rh0 = *(const bf16x8*)&WrH[oc * 64 + kb];
            bf16x8 rh1 = *(const bf16x8*)&WrH[oc * 64 + 32 + kb];
            bf16x8 rl0 = *(const bf16x8*)&WrL[oc * 64 + kb];
            bf16x8 rl1 = *(const bf16x8*)&WrL[oc * 64 + 32 + kb];
            acc = __builtin_amdgcn_mfma_f32_16x16x32_bf16(hs0, rh0, acc, 0, 0, 0);
            acc = __builtin_amdgcn_mfma_f32_16x16x32_bf16(hs1, rh1, acc, 0, 0, 0);
            acc = __builtin_amdgcn_mfma_f32_16x16x32_bf16(hs0, rl0, acc, 0, 0, 0);
            acc = __builtin_amdgcn_mfma_f32_16x16x32_bf16(hs1, rl1, acc, 0, 0, 0);
            #pragma unroll
            for (int r = 0; r < 4; r++) {
                float v = acc[r] > 0.f ? acc[r] : 0.f;
                sO[(quad * 4 + r) * 68 + oc] = (uint16_t)rne_bf16(v);
            }
        }
        asm volatile("s_waitcnt lgkmcnt(0)" ::: "memory");
        __builtin_amdgcn_sched_barrier(0);
        // write-out: 16 nodes x 32 dwords, 64 lanes -> 8 iters
        const uint32_t* sOd = (const uint32_t*)sO;
        uint32_t* Hd = (uint32_t*)Hout;
        #pragma unroll
        for (int it = 0; it < 8; it++) {
            int idx = it * 64 + c;
            int nd = idx >> 5, col = idx & 31;
            Hd[(n0 + nd) * 32 + col] = sOd[nd * 34 + col];
        }
    } else {
        float pa[4] = {0.f, 0.f, 0.f, 0.f};
        float pr[4] = {0.f, 0.f, 0.f, 0.f};
        #pragma unroll
        for (int ob = 0; ob < 4; ob++) {
            int oc = ob * 16 + row;
            float bias = brel[oc];
            f32x4 acc = {bias, bias, bias, bias};
            bf16x8 gh0 = *(const bf16x8*)&WgH[oc * 64 + kb];
            bf16x8 gh1 = *(const bf16x8*)&WgH[oc * 64 + 32 + kb];
            bf16x8 gl0 = *(const bf16x8*)&WgL[oc * 64 + kb];
            bf16x8 gl1 = *(const bf16x8*)&WgL[oc * 64 + 32 + kb];
            acc = __builtin_amdgcn_mfma_f32_16x16x32_bf16(ah0, gh0, acc, 0, 0, 0);
            acc = __builtin_amdgcn_mfma_f32_16x16x32_bf16(ah1, gh1, acc, 0, 0, 0);
            acc = __builtin_amdgcn_mfma_f32_16x16x32_bf16(ah0, gl0, acc, 0, 0, 0);
            acc = __builtin_amdgcn_mfma_f32_16x16x32_bf16(ah1, gl1, acc, 0, 0, 0);
            bf16x8 rh0 = *(const bf16x8*)&WrH[oc * 64 + kb];
            bf16x8 rh1 = *(const bf16x8*)&WrH[oc * 64 + 32 + kb];
            bf16x8 rl0 = *(const bf16x8*)&WrL[oc * 64 + kb];
            bf16x8 rl1 = *(const bf16x8*)&WrL[oc * 64 + 32 + kb];
            acc = __builtin_amdgcn_mfma_f32_16x16x32_bf16(hs0, rh0, acc, 0, 0, 0);
            acc = __builtin_amdgcn_mfma_f32_16x16x32_bf16(hs1, rh1, acc, 0, 0, 0);
            acc = __builtin_amdgcn_mfma_f32_16x16x32_bf16(hs0, rl0, acc, 0, 0, 0);
            acc = __builtin_amdgcn_mfma_f32_16x16x32_bf16(hs1, rl1, acc, 0, 0, 0);
            float wlc = WrelL[oc], woc = WrootL[oc];
            #pragma unroll
            for (int r = 0; r < 4; r++) {
                float v = acc[r] > 0.f ? acc[r] : 0.f;
                pa[r] += v * wlc;
                pr[r] += v * woc;
            }
        }
        #pragma unroll
        for (int r = 0; r < 4; r++) {
            #pragma unroll
            for (int o = 8; o > 0; o >>= 1) {
                pa[r] += __shfl_down(pa[r], o, 16);
                pr[r] += __shfl_down(pr[r], o, 16);
            }
            if (row == 0) {
                int node = n0 + quad * 4 + r;
                sarr[node] = pa[r];
                rarr[node] = pr[r];
            }
        }
    }
}

// final edge pass: wave-per-4-nodes edge-parallel gather + shfl reduce
__global__ __launch_bounds__(256) void k_last(
        const int* __restrict__ offs, const int* __restrict__ ends,
        const uint32_t* __restrict__ pairs,
        const float* __restrict__ sarr, const float* __restrict__ rarr,
        const float* __restrict__ brelL, float* __restrict__ out) {
    int c = threadIdx.x & 63;
    int w = threadIdx.x >> 6;
    int blk16 = blockIdx.x * 16;
    float b0 = brelL[0];
    #pragma unroll
    for (int t = 0; t < 4; t++) {
        int node = blk16 + w * 4 + t;
        int b = offs[node], e = ends[node];
        float pp = 0.f;
        for (int j = b + c; j < e; j += 64) {
            uint32_t r = pairs[j];
            pp += __uint_as_float((r >> 17) << 16) * sarr[r & 0x1ffffu];
        }
        #pragma unroll
        for (int o = 32; o > 0; o >>= 1) pp += __shfl_down(pp, o, 64);
        if (c == 0) out[node] = pp + rarr[node] + b0;
    }
}

extern "C" void kernel_launch(void* const* d_in, const int* in_sizes, int n_in,
                              void* d_out, int out_size, void* d_ws, size_t ws_size,
                              hipStream_t stream) {
    const float* x        = (const float*)d_in[0];
    const int*   ei       = (const int*)d_in[1];
    const float* ew       = (const float*)d_in[2];
    const float* Wrel0    = (const float*)d_in[3];
    const float* brel0    = (const float*)d_in[4];
    const float* Wroot0   = (const float*)d_in[5];
    const float* Wrel_mid = (const float*)d_in[6];
    const float* brel_mid = (const float*)d_in[7];
    const float* Wroot_mid= (const float*)d_in[8];
    const float* WrelL    = (const float*)d_in[9];
    const float* brelL    = (const float*)d_in[10];
    const float* WrootL   = (const float*)d_in[11];
    float* out = (float*)d_out;

    const int* src  = ei;
    const int* dstp = ei + NE;

    char* w = (char*)d_ws;
    size_t o = 0;
    auto alloc = [&](size_t b) -> void* {
        void* r = (void*)(w + o);
        o += (b + 255) & ~(size_t)255;
        return r;
    };
    int*      offs  = (int*)alloc((size_t)NN * 4);
    int*      ends  = (int*)alloc((size_t)NN * 4);
    int*      bcur  = (int*)alloc((size_t)NBKT * 4);
    uint16_t* WgH   = (uint16_t*)alloc((size_t)3 * 4096 * 2);
    uint16_t* WgL   = (uint16_t*)alloc((size_t)3 * 4096 * 2);
    uint16_t* WrH   = (uint16_t*)alloc((size_t)3 * 4096 * 2);
    uint16_t* WrL   = (uint16_t*)alloc((size_t)3 * 4096 * 2);
    float*    sarr  = (float*)alloc((size_t)NN * 4);
    float*    rarr  = (float*)alloc((size_t)NN * 4);
    uint32_t* pairs = (uint32_t*)alloc((size_t)NBKT * CAP * 4);  // 12.8 MB padded
    uint16_t* HbA   = (uint16_t*)alloc((size_t)NN * HID * 2);    // 12.8 MB
    uint16_t* HbB   = (uint16_t*)alloc((size_t)NN * HID * 2);
    uint16_t* spare = (uint16_t*)alloc((size_t)NN * HID * 2);    // bpairs tail
    (void)spare;
    // bpairs (NBKT*CAP*8B = 25.6MB) aliases HbB+spare (contiguous; dead
    // before mid layer 1 writes HbB)
    int2*  bpairs = (int2*)HbB;

    // weight split + bucket cursor init (one launch)
    k_wsplit<<<(3 * 4096 + 255) / 256, 256, 0, stream>>>(
        Wrel_mid, Wroot_mid, WgH, WgL, WrH, WrL, bcur);

    // CSR build (padded buckets)
    k_bpart<<<NTILE, 256, 0, stream>>>(src, dstp, ew, bcur, bpairs);
    k_bcsr<<<NBKT, 256, 0, stream>>>(bcur, bpairs, offs, ends, pairs);

    // layer 0: h1 (bf16 rows) -> HbA
    k_l0pre<<<NN / 16, 256, 0, stream>>>(
        offs, ends, pairs, x, Wrel0, brel0, Wroot0, HbA);

    int nagg = NN / 16;   // 6250 one-wave blocks, 16 nodes each
    // mid layer 1: h1 -> h2 (weights idx 0)
    k_aggfused<false><<<nagg, 64, 0, stream>>>(
        offs, ends, pairs, HbA,
        WgH, WgL, WrH, WrL, brel_mid,
        HbB, WrelL, WrootL, sarr, rarr);
    // mid layer 2: h2 -> h3 (weights idx 1)
    k_aggfused<false><<<nagg, 64, 0, stream>>>(
        offs, ends, pairs, HbB,
        WgH + 4096, WgL + 4096, WrH + 4096, WrL + 4096, brel_mid + HID,
        HbA, WrelL, WrootL, sarr, rarr);
    // mid layer 3 (LAST): h3 -> sarr/rarr (weights idx 2)
    k_aggfused<true><<<nagg, 64, 0, stream>>>(
        offs, ends, pairs, HbA,
        WgH + 2 * 4096, WgL + 2 * 4096, WrH + 2 * 4096, WrL + 2 * 4096,
        brel_mid + 2 * HID,
        HbB, WrelL, WrootL, sarr, rarr);

    // final edge pass on scalars
    k_last<<<NN / 16, 256, 0, stream>>>(offs, ends, pairs, sarr, rarr, brelL, out);
}

// Round 12
// 287.534 us; speedup vs baseline: 1.1038x; 1.0033x over previous
//
#include <hip/hip_runtime.h>
#include <stdint.h>

// GraphConv x5 on MI355X — round 31.
// vs round 30 (288.5us; mid layers pinned at ~47.7us, beyond-L2 ~98MB @
// 2.06TB/s service ceiling — gather-traffic floor for rank-64 h): h1 is
// RANK-2 (1 input feature): h1[s] = relu(aggx_s*Wrel0 + brel0 + x_s*Wroot0).
// Mid-layer-1 (k_agg1) gathers 8B (aggx,x) per edge (800KB L2-resident
// table) instead of 128B h1 rows, reconstructing B-fragments in-register
// with IDENTICAL f32 math + rne_bf16 (bit-identical h1). l0pre now writes
// only AX (0.8MB, no MFMA epilogue). Mid-2/3 unchanged (rank-64).

#define NN 100000
#define NE 1600000
#define HID 64
#define NBKT 391            // ceil(NN/256), bucket = dst >> 8
#define CAP 8192            // padded bucket capacity (mean 4092, +64 sigma)
#define PMAX (NBKT * CAP)
#define TILE 4096
#define EPT 16              // TILE / 256
#define NTILE ((NE + TILE - 1) / TILE)   // 391

typedef __attribute__((ext_vector_type(8))) short bf16x8;
typedef __attribute__((ext_vector_type(4))) float f32x4;
typedef __attribute__((ext_vector_type(2))) unsigned int u32x2;
typedef __attribute__((ext_vector_type(4))) unsigned int u32x4;

__device__ __forceinline__ uint32_t rne_bf16(float v) {
    uint32_t u = __float_as_uint(v);
    return (u + 0x7fffu + ((u >> 16) & 1u)) >> 16;
}

// ---------------- CSR build ----------------

// tile-local LDS counting sort + coalesced segment write-out
__global__ __launch_bounds__(256) void k_bpart(const int* __restrict__ src,
                                               const int* __restrict__ dst,
                                               const float* __restrict__ w,
                                               int* __restrict__ bcur,
                                               int2* __restrict__ bpairs) {
    __shared__ int  hcnt[NBKT];      // count, then cursor
    __shared__ int  hoff[NBKT];      // local exclusive offset
    __shared__ int  hadj[NBKT];      // global base - local offset
    __shared__ int  sc0[512];
    __shared__ int  sc1[512];
    __shared__ int2 sT[TILE];        // 32 KB staged tile (bucket-sorted)
    __shared__ int  sAdj[TILE];      // 16 KB per-slot global adjust
    int tile0 = blockIdx.x * TILE;
    int t = threadIdx.x;
    for (int i = t; i < NBKT; i += 256) hcnt[i] = 0;
    __syncthreads();

    int   pk[EPT];
    int   bk[EPT];
    float wv[EPT];
    #pragma unroll
    for (int k = 0; k < EPT; k++) {
        int e = tile0 + t + k * 256;
        if (e < NE) {
            int d = dst[e];
            int b = d >> 8;
            pk[k] = (src[e] << 8) | (d & 255);
            wv[k] = w[e];
            bk[k] = b;
            atomicAdd(&hcnt[b], 1);
        } else {
            bk[k] = -1;
        }
    }
    __syncthreads();

    // inclusive scan of hcnt over 512 (padded) with ping-pong buffers
    sc0[t]       = (t < NBKT) ? hcnt[t] : 0;
    sc0[t + 256] = (t + 256 < NBKT) ? hcnt[t + 256] : 0;
    __syncthreads();
    int* cur = sc0;
    int* oth = sc1;
    for (int off = 1; off < 512; off <<= 1) {
        int v0 = cur[t]       + ((t       >= off) ? cur[t - off]       : 0);
        int v1 = cur[t + 256] + ((t + 256 >= off) ? cur[t + 256 - off] : 0);
        oth[t] = v0;
        oth[t + 256] = v1;
        __syncthreads();
        int* tmp = cur; cur = oth; oth = tmp;
    }
    for (int i = t; i < NBKT; i += 256) {
        int c = hcnt[i];
        int excl = cur[i] - c;
        hoff[i] = excl;
        int gbase = c ? atomicAdd(&bcur[i], c) : 0;
        hadj[i] = gbase - excl;
        hcnt[i] = 0;                 // reuse as local cursor
    }
    __syncthreads();

    // scatter into LDS (bucket-sorted order)
    #pragma unroll
    for (int k = 0; k < EPT; k++) {
        if (bk[k] >= 0) {
            int b = bk[k];
            int pos = hoff[b] + atomicAdd(&hcnt[b], 1);
            sT[pos] = make_int2(pk[k], __float_as_int(wv[k]));
            sAdj[pos] = hadj[b];
        }
    }
    __syncthreads();

    // linear write-out: consecutive slots in a bucket run -> consecutive
    // global addresses (coalesced bursts)
    int n = NE - tile0; if (n > TILE) n = TILE;
    for (int j = t; j < n; j += 256)
        bpairs[sAdj[j] + j] = sT[j];
}

// one block per bucket: stage bucket in LDS, then LDS counting sort.
__global__ __launch_bounds__(256) void k_bcsr(const int* __restrict__ bcur,
                                              const int2* __restrict__ bpairs,
                                              int* __restrict__ offs,
                                              int* __restrict__ ends,
                                              uint32_t* __restrict__ pairs) {
    __shared__ int2 sE[CAP];        // 64 KB bucket stage
    __shared__ int cnt[256];
    __shared__ int scn[256];
    __shared__ int cur[256];
    int k = blockIdx.x, t = threadIdx.x;
    int base = k * CAP;
    int scnt = bcur[k] - base;
    cnt[t] = 0;
    __syncthreads();
    for (int j = t; j < scnt; j += 256) {
        int2 q = bpairs[base + j];
        sE[j] = q;
        atomicAdd(&cnt[q.x & 255], 1);
    }
    __syncthreads();
    int v = cnt[t], acc = v;
    scn[t] = v;
    __syncthreads();
    for (int off = 1; off < 256; off <<= 1) {
        int u = (t >= off) ? scn[t - off] : 0;
        __syncthreads();
        acc += u;
        scn[t] = acc;
        __syncthreads();
    }
    int excl = acc - v;
    cur[t] = excl;
    int d = (k << 8) + t;
    if (d < NN) {
        offs[d] = base + excl;
        ends[d] = base + excl + v;
    }
    __syncthreads();
    for (int j = t; j < scnt; j += 256) {
        int2 q = sE[j];
        int pos = base + atomicAdd(&cur[q.x & 255], 1);
        uint32_t wb = rne_bf16(__int_as_float(q.y)) & 0x7fffu;   // w >= 0
        pairs[pos] = (wb << 17) | (uint32_t)(q.x >> 8);
    }
}

// ---------------- weight hi/lo split (+ bucket cursor init) ----------------

__global__ __launch_bounds__(256) void k_wsplit(const float* __restrict__ Wrel_mid,
                                                const float* __restrict__ Wroot_mid,
                                                uint16_t* __restrict__ WgH,
                                                uint16_t* __restrict__ WgL,
                                                uint16_t* __restrict__ WrH,
                                                uint16_t* __restrict__ WrL,
                                                int* __restrict__ bcur) {
    int i = blockIdx.x * blockDim.x + threadIdx.x;
    if (i < NBKT) bcur[i] = i * CAP;
    if (i >= 3 * 4096) return;
    float a = Wrel_mid[i];
    uint32_t ah = rne_bf16(a);
    float al = a - __uint_as_float(ah << 16);
    WgH[i] = (uint16_t)ah;
    WgL[i] = (uint16_t)rne_bf16(al);
    float b = Wroot_mid[i];
    uint32_t bh = rne_bf16(b);
    float bl = b - __uint_as_float(bh << 16);
    WrH[i] = (uint16_t)bh;
    WrL[i] = (uint16_t)rne_bf16(bl);
}

// ---------------- layers ----------------

// layer 0: edge-parallel aggregation (4 nodes/wave, shfl reduce); writes
// ONLY the rank-2 state AX[node] = (aggx, x) — h1 is reconstructed by
// consumers.
__global__ __launch_bounds__(256) void k_l0pre(
        const int* __restrict__ offs, const int* __restrict__ ends,
        const uint32_t* __restrict__ pairs, const float* __restrict__ x,
        float2* __restrict__ AX) {
    int c = threadIdx.x & 63;
    int w = threadIdx.x >> 6;
    int blk16 = blockIdx.x * 16;
    #pragma unroll
    for (int t = 0; t < 4; t++) {
        int node = blk16 + w * 4 + t;
        int b = offs[node], e = ends[node];
        float pp = 0.f;
        for (int j = b + c; j < e; j += 64) {
            uint32_t r = pairs[j];
            pp += __uint_as_float((r >> 17) << 16) * x[r & 0x1ffffu];
        }
        for (int o = 32; o > 0; o >>= 1) pp += __shfl_down(pp, o, 64);
        if (c == 0) AX[node] = make_float2(pp, x[node]);
    }
}

// transpose-read, byte-addressed: column = addr bits[6:3], subtile = the
// 128B-aligned base; lane reads bytes (addr&~127) + ((addr>>3)&15)*2 + 32*j
#define TRRA(dst, off) \
    asm volatile("ds_read_b64_tr_b16 %0, %1 offset:" #off \
                 : "=v"(dst) : "v"(trbA))
#define TRRB(dst, off) \
    asm volatile("ds_read_b64_tr_b16 %0, %1 offset:" #off \
                 : "=v"(dst) : "v"(trbB))

// Mid layer 1 (rank-2 input): gather 8B (aggx,x) per edge, reconstruct
// h1 B-fragments in-register (identical f32 math + rne_bf16 -> bit-
// identical to materialized h1), MFMA consume, standard epilogue ->
// h2 rows. No LDS gather stage at all.
__global__ __launch_bounds__(64, 4) void k_agg1(
        const int* __restrict__ offs, const int* __restrict__ ends,
        const uint32_t* __restrict__ pairs,
        const float2* __restrict__ AX,
        const float* __restrict__ Wrel0, const float* __restrict__ brel0,
        const float* __restrict__ Wroot0,
        const uint16_t* __restrict__ WgH, const uint16_t* __restrict__ WgL,
        const uint16_t* __restrict__ WrH, const uint16_t* __restrict__ WrL,
        const float* __restrict__ brel,
        uint16_t* __restrict__ Hout) {
    __shared__ __align__(128) char smem[4608];   // sH 2304 + sO 2176
    int c = threadIdx.x;                  // 0..63
    int n0 = blockIdx.x * 16;
    int row = c & 15;
    int quad = c >> 4;
    int kq = quad * 8;

    int myNode = n0 + row;
    int blo = offs[myNode];
    int bhi = ends[myNode];
    uint32_t wid = (uint32_t)(bhi - blo);
    int start  = __builtin_amdgcn_readlane(blo, 0);
    int finish = __builtin_amdgcn_readlane(bhi, 15);

    // per-lane B-column weights (col = nb*16 + row)
    float wrc[4], brc[4], woc[4];
    #pragma unroll
    for (int nb = 0; nb < 4; nb++) {
        int col = nb * 16 + row;
        wrc[nb] = Wrel0[col]; brc[nb] = brel0[col]; woc[nb] = Wroot0[col];
    }

    f32x4 acc16[4];
    #pragma unroll
    for (int nb = 0; nb < 4; nb++) acc16[nb] = f32x4{0.f, 0.f, 0.f, 0.f};

    int j0 = start + c; if (j0 > PMAX - 1) j0 = PMAX - 1;
    uint32_t praw = pairs[j0];
    uint32_t p = (start + c < finish) ? praw : 0;

    for (int cb = start; cb < finish; cb += 64) {
        int jn = cb + 64 + c; if (jn > PMAX - 1) jn = PMAX - 1;
        uint32_t pr2 = pairs[jn];
        float2 ax = AX[p & 0x1ffffu];     // 8B gather (L2-resident table)
        // A fragments (masked weights) under the load shadow
        uint32_t mA[8], mB[8];
        int dbA = cb + kq - blo;
        int dbB = cb + 32 + kq - blo;
        #pragma unroll
        for (int q = 0; q < 8; q++) {
            uint32_t rq = (uint32_t)__builtin_amdgcn_ds_bpermute(
                (kq + q) * 4, (int)p);
            mA[q] = ((uint32_t)(dbA + q) < wid) ? (rq >> 17) : 0u;
        }
        #pragma unroll
        for (int q = 0; q < 8; q++) {
            uint32_t rq = (uint32_t)__builtin_amdgcn_ds_bpermute(
                (32 + kq + q) * 4, (int)p);
            mB[q] = ((uint32_t)(dbB + q) < wid) ? (rq >> 17) : 0u;
        }
        u32x4 aav = { mA[0] | (mA[1] << 16), mA[2] | (mA[3] << 16),
                      mA[4] | (mA[5] << 16), mA[6] | (mA[7] << 16) };
        u32x4 abv = { mB[0] | (mB[1] << 16), mB[2] | (mB[3] << 16),
                      mB[4] | (mB[5] << 16), mB[6] | (mB[7] << 16) };
        bf16x8 afA = __builtin_bit_cast(bf16x8, aav);
        bf16x8 afB = __builtin_bit_cast(bf16x8, abv);
        asm volatile("s_waitcnt vmcnt(0)" ::: "memory");  // ax + pr2 ready
        int areg = __float_as_int(ax.x);
        int xreg = __float_as_int(ax.y);
        #pragma unroll
        for (int s = 0; s < 2; s++) {
            // redistribute (a,x) for this lane's 8 k-slots
            float av[8], xv[8];
            #pragma unroll
            for (int q = 0; q < 8; q++) {
                int idx = (s * 32 + kq + q) * 4;
                av[q] = __int_as_float(__builtin_amdgcn_ds_bpermute(idx, areg));
                xv[q] = __int_as_float(__builtin_amdgcn_ds_bpermute(idx, xreg));
            }
            bf16x8 af = s ? afB : afA;
            #pragma unroll
            for (int nb = 0; nb < 4; nb++) {
                uint32_t hh[8];
                #pragma unroll
                for (int q = 0; q < 8; q++) {
                    float h = av[q] * wrc[nb] + brc[nb] + xv[q] * woc[nb];
                    h = h > 0.f ? h : 0.f;
                    hh[q] = rne_bf16(h);
                }
                u32x4 bb = { hh[0] | (hh[1] << 16), hh[2] | (hh[3] << 16),
                             hh[4] | (hh[5] << 16), hh[6] | (hh[7] << 16) };
                acc16[nb] = __builtin_amdgcn_mfma_f32_16x16x32_bf16(
                    af, __builtin_bit_cast(bf16x8, bb), acc16[nb], 0, 0, 0);
            }
        }
        p = (cb + 64 + c < finish) ? pr2 : 0;
    }

    // ---- epilogue: h2 = relu(Wrel1.agg + Wroot1.h1_self + brel1) ----
    // h1_self fragments reconstructed from AX[n0+row]
    float2 axs = AX[n0 + row];
    uint32_t e0[8], e1[8];
    #pragma unroll
    for (int q = 0; q < 8; q++) {
        int k0 = kq + q;
        float h = axs.x * Wrel0[k0] + brel0[k0] + axs.y * Wroot0[k0];
        h = h > 0.f ? h : 0.f;
        e0[q] = rne_bf16(h);
        int k1 = 32 + kq + q;
        float h2 = axs.x * Wrel0[k1] + brel0[k1] + axs.y * Wroot0[k1];
        h2 = h2 > 0.f ? h2 : 0.f;
        e1[q] = rne_bf16(h2);
    }
    u32x4 hv0 = { e0[0] | (e0[1] << 16), e0[2] | (e0[3] << 16),
                  e0[4] | (e0[5] << 16), e0[6] | (e0[7] << 16) };
    u32x4 hv1 = { e1[0] | (e1[1] << 16), e1[2] | (e1[3] << 16),
                  e1[4] | (e1[5] << 16), e1[6] | (e1[7] << 16) };
    bf16x8 hs0 = __builtin_bit_cast(bf16x8, hv0);
    bf16x8 hs1 = __builtin_bit_cast(bf16x8, hv1);

    // pack agg (NO relu) -> sH
    uint32_t* sHw = (uint32_t*)smem;
    #pragma unroll
    for (int t = 0; t < 4; t++) {
        #pragma unroll
        for (int nb = 0; nb < 4; nb++) {
            uint32_t hb = rne_bf16(acc16[nb][t]);
            uint32_t pn2 = (uint32_t)__shfl_xor((int)hb, 1, 64);
            if (!(c & 1))
                sHw[(quad * 4 + t) * 36 + nb * 8 + (row >> 1)]
                    = hb | (pn2 << 16);
        }
    }
    asm volatile("s_waitcnt lgkmcnt(0)" ::: "memory");
    __builtin_amdgcn_sched_barrier(0);
    int kb = quad * 8;
    bf16x8 ah0 = *(const bf16x8*)&sHw[row * 36 + quad * 4];
    bf16x8 ah1 = *(const bf16x8*)&sHw[row * 36 + 16 + quad * 4];

    uint16_t* sO = (uint16_t*)(smem + 2304);
    #pragma unroll
    for (int ob = 0; ob < 4; ob++) {
        int oc = ob * 16 + row;
        float bias = brel[oc];
        f32x4 acc = {bias, bias, bias, bias};
        bf16x8 gh0 = *(const bf16x8*)&WgH[oc * 64 + kb];
        bf16x8 gh1 = *(const bf16x8*)&WgH[oc * 64 + 32 + kb];
        bf16x8 gl0 = *(const bf16x8*)&WgL[oc * 64 + kb];
        bf16x8 gl1 = *(const bf16x8*)&WgL[oc * 64 + 32 + kb];
        acc = __builtin_amdgcn_mfma_f32_16x16x32_bf16(ah0, gh0, acc, 0, 0, 0);
        acc = __builtin_amdgcn_mfma_f32_16x16x32_bf16(ah1, gh1, acc, 0, 0, 0);
        acc = __builtin_amdgcn_mfma_f32_16x16x32_bf16(ah0, gl0, acc, 0, 0, 0);
        acc = __builtin_amdgcn_mfma_f32_16x16x32_bf16(ah1, gl1, acc, 0, 0, 0);
        bf16x8 rh0 = *(const bf16x8*)&WrH[oc * 64 + kb];
        bf16x8 rh1 = *(const bf16x8*)&WrH[oc * 64 + 32 + kb];
        bf16x8 rl0 = *(const bf16x8*)&WrL[oc * 64 + kb];
        bf16x8 rl1 = *(const bf16x8*)&WrL[oc * 64 + 32 + kb];
        acc = __builtin_amdgcn_mfma_f32_16x16x32_bf16(hs0, rh0, acc, 0, 0, 0);
        acc = __builtin_amdgcn_mfma_f32_16x16x32_bf16(hs1, rh1, acc, 0, 0, 0);
        acc = __builtin_amdgcn_mfma_f32_16x16x32_bf16(hs0, rl0, acc, 0, 0, 0);
        acc = __builtin_amdgcn_mfma_f32_16x16x32_bf16(hs1, rl1, acc, 0, 0, 0);
        #pragma unroll
        for (int r = 0; r < 4; r++) {
            float v = acc[r] > 0.f ? acc[r] : 0.f;
            sO[(quad * 4 + r) * 68 + oc] = (uint16_t)rne_bf16(v);
        }
    }
    asm volatile("s_waitcnt lgkmcnt(0)" ::: "memory");
    __builtin_amdgcn_sched_barrier(0);
    const uint32_t* sOd = (const uint32_t*)sO;
    uint32_t* Hd = (uint32_t*)Hout;
    #pragma unroll
    for (int it = 0; it < 8; it++) {
        int idx = it * 64 + c;
        int nd = idx >> 5, col = idx & 31;
        Hd[(n0 + nd) * 32 + col] = sOd[nd * 34 + col];
    }
}

// Mid layer (rank-64): gather h rows (r28 schedule), agg via MFMA
// (C-init 0), epilogue h_next = relu(Wrel.agg + Wroot.h_self + brel).
// LAST: epilogue then width-16 shfl dots with WrelL/WrootL -> sarr/rarr.
template <bool LAST>
__global__ __launch_bounds__(64, 5) void k_aggfused(
        const int* __restrict__ offs, const int* __restrict__ ends,
        const uint32_t* __restrict__ pairs,
        const uint16_t* __restrict__ Hb,
        const uint16_t* __restrict__ WgH, const uint16_t* __restrict__ WgL,
        const uint16_t* __restrict__ WrH, const uint16_t* __restrict__ WrL,
        const float* __restrict__ brel,
        uint16_t* __restrict__ Hout,
        const float* __restrict__ WrelL, const float* __restrict__ WrootL,
        float* __restrict__ sarr, float* __restrict__ rarr) {
    __shared__ __align__(128) char smem[8192];
    int c = threadIdx.x;                  // 0..63
    int n0 = blockIdx.x * 16;             // wave owns nodes [n0, n0+16)

    int myNode = n0 + (c & 15);
    int blo = offs[myNode];
    int bhi = ends[myNode];
    uint32_t wid = (uint32_t)(bhi - blo);
    int start  = __builtin_amdgcn_readlane(blo, 0);
    int finish = __builtin_amdgcn_readlane(bhi, 15);

    int kq = (c >> 4) * 8;                // MFMA k-base for this quad
    int eprm  = ((c >> 5) << 2) | ((c >> 1) & 3);
    int lbyte = ((c >> 3) & 3) * 32 + (c & 1) * 16;
    char* stg = smem;                     // chunk A: stg, chunk B: +4096
    uint32_t stgOff = (uint32_t)(uintptr_t)
        (__attribute__((address_space(3))) char*)stg;
    uint32_t trbA = stgOff + ((uint32_t)(c >> 4) << 10)
                          + ((uint32_t)(c & 15) << 3);
    uint32_t trbB = trbA + 4096;

    f32x4 acc16[4];
    #pragma unroll
    for (int nb = 0; nb < 4; nb++) acc16[nb] = f32x4{0.f, 0.f, 0.f, 0.f};

    const char* gbase = (const char*)Hb;
    int j0 = start + c; if (j0 > PMAX - 1) j0 = PMAX - 1;
    uint32_t praw = pairs[j0];
    uint32_t p = (start + c < finish) ? praw : 0;

    for (int cb = start; cb < finish; cb += 64) {
        int jn = cb + 64 + c; if (jn > PMAX - 1) jn = PMAX - 1;
        uint32_t pr2 = pairs[jn];                               // vmem 1
        #pragma unroll
        for (int i = 0; i < 4; i++) {                           // vmem 2-5
            uint32_t r = (uint32_t)__builtin_amdgcn_ds_bpermute(
                (eprm + i * 8) * 4, (int)p);
            uint32_t voff = ((r & 0x1ffffu) << 7) + (uint32_t)lbyte;
            __builtin_amdgcn_global_load_lds(
                (const __attribute__((address_space(1))) void*)(gbase + voff),
                (__attribute__((address_space(3))) void*)(stg + i * 1024),
                16, 0, 0);
        }
        #pragma unroll
        for (int i = 0; i < 4; i++) {                           // vmem 6-9
            uint32_t r = (uint32_t)__builtin_amdgcn_ds_bpermute(
                (32 + eprm + i * 8) * 4, (int)p);
            uint32_t voff = ((r & 0x1ffffu) << 7) + (uint32_t)lbyte;
            __builtin_amdgcn_global_load_lds(
                (const __attribute__((address_space(1))) void*)(gbase + voff),
                (__attribute__((address_space(3))) void*)(stg + 4096 + i * 1024),
                16, 0, 0);
        }
        uint32_t mA[8], mB[8];
        int dbA = cb + kq - blo;
        int dbB = cb + 32 + kq - blo;
        #pragma unroll
        for (int q = 0; q < 8; q++) {
            uint32_t rq = (uint32_t)__builtin_amdgcn_ds_bpermute(
                (kq + q) * 4, (int)p);
            mA[q] = ((uint32_t)(dbA + q) < wid) ? (rq >> 17) : 0u;
        }
        #pragma unroll
        for (int q = 0; q < 8; q++) {
            uint32_t rq = (uint32_t)__builtin_amdgcn_ds_bpermute(
                (32 + kq + q) * 4, (int)p);
            mB[q] = ((uint32_t)(dbB + q) < wid) ? (rq >> 17) : 0u;
        }
        u32x4 aav = { mA[0] | (mA[1] << 16), mA[2] | (mA[3] << 16),
                      mA[4] | (mA[5] << 16), mA[6] | (mA[7] << 16) };
        u32x4 abv = { mB[0] | (mB[1] << 16), mB[2] | (mB[3] << 16),
                      mB[4] | (mB[5] << 16), mB[6] | (mB[7] << 16) };
        bf16x8 afA = __builtin_bit_cast(bf16x8, aav);
        bf16x8 afB = __builtin_bit_cast(bf16x8, abv);
        asm volatile("s_waitcnt vmcnt(4)" ::: "memory");
        {
            u32x2 tb0, tb1, tb2, tb3, tb4, tb5, tb6, tb7;
            TRRA(tb0, 0);   TRRA(tb1, 512);
            TRRA(tb2, 128); TRRA(tb3, 640);
            TRRA(tb4, 256); TRRA(tb5, 768);
            TRRA(tb6, 384); TRRA(tb7, 896);
            asm volatile("s_waitcnt lgkmcnt(0)" ::: "memory");
            __builtin_amdgcn_sched_barrier(0);
            u32x4 bb0 = { tb0.x, tb0.y, tb1.x, tb1.y };
            acc16[0] = __builtin_amdgcn_mfma_f32_16x16x32_bf16(
                afA, __builtin_bit_cast(bf16x8, bb0), acc16[0], 0, 0, 0);
            u32x4 bb1 = { tb2.x, tb2.y, tb3.x, tb3.y };
            acc16[1] = __builtin_amdgcn_mfma_f32_16x16x32_bf16(
                afA, __builtin_bit_cast(bf16x8, bb1), acc16[1], 0, 0, 0);
            u32x4 bb2 = { tb4.x, tb4.y, tb5.x, tb5.y };
            acc16[2] = __builtin_amdgcn_mfma_f32_16x16x32_bf16(
                afA, __builtin_bit_cast(bf16x8, bb2), acc16[2], 0, 0, 0);
            u32x4 bb3 = { tb6.x, tb6.y, tb7.x, tb7.y };
            acc16[3] = __builtin_amdgcn_mfma_f32_16x16x32_bf16(
                afA, __builtin_bit_cast(bf16x8, bb3), acc16[3], 0, 0, 0);
        }
        asm volatile("s_waitcnt vmcnt(0)" ::: "memory");
        {
            u32x2 tb0, tb1, tb2, tb3, tb4, tb5, tb6, tb7;
            TRRB(tb0, 0);   TRRB(tb1, 512);
            TRRB(tb2, 128); TRRB(tb3, 640);
            TRRB(tb4, 256); TRRB(tb5, 768);
            TRRB(tb6, 384); TRRB(tb7, 896);
            asm volatile("s_waitcnt lgkmcnt(0)" ::: "memory");
            __builtin_amdgcn_sched_barrier(0);
            u32x4 bb0 = { tb0.x, tb0.y, tb1.x, tb1.y };
            acc16[0] = __builtin_amdgcn_mfma_f32_16x16x32_bf16(
                afB, __builtin_bit_cast(bf16x8, bb0), acc16[0], 0, 0, 0);
            u32x4 bb1 = { tb2.x, tb2.y, tb3.x, tb3.y };
            acc16[1] = __builtin_amdgcn_mfma_f32_16x16x32_bf16(
                afB, __builtin_bit_cast(bf16x8, bb1), acc16[1], 0, 0, 0);
            u32x4 bb2 = { tb4.x, tb4.y, tb5.x, tb5.y };
            acc16[2] = __builtin_amdgcn_mfma_f32_16x16x32_bf16(
                afB, __builtin_bit_cast(bf16x8, bb2), acc16[2], 0, 0, 0);
            u32x4 bb3 = { tb6.x, tb6.y, tb7.x, tb7.y };
            acc16[3] = __builtin_amdgcn_mfma_f32_16x16x32_bf16(
                afB, __builtin_bit_cast(bf16x8, bb3), acc16[3], 0, 0, 0);
        }
        p = (cb + 64 + c < finish) ? pr2 : 0;
    }
    asm volatile("s_waitcnt vmcnt(0)" ::: "memory");

    // ---- shared epilogue: h' = Wrel.agg + Wroot.h_self + brel ----
    int row = c & 15;
    int quad = c >> 4;
    int kb = quad * 8;
    bf16x8 hs0 = *(const bf16x8*)&Hb[(n0 + row) * 64 + kb];
    bf16x8 hs1 = *(const bf16x8*)&Hb[(n0 + row) * 64 + 32 + kb];
    uint32_t* sHw = (uint32_t*)smem;
    #pragma unroll
    for (int t = 0; t < 4; t++) {
        #pragma unroll
        for (int nb = 0; nb < 4; nb++) {
            uint32_t hb = rne_bf16(acc16[nb][t]);
            uint32_t pn2 = (uint32_t)__shfl_xor((int)hb, 1, 64);
            if (!(c & 1))
                sHw[(quad * 4 + t) * 36 + nb * 8 + (row >> 1)]
                    = hb | (pn2 << 16);
        }
    }
    asm volatile("s_waitcnt lgkmcnt(0)" ::: "memory");
    __builtin_amdgcn_sched_barrier(0);
    bf16x8 ah0 = *(const bf16x8*)&sHw[row * 36 + quad * 4];
    bf16x8 ah1 = *(const bf16x8*)&sHw[row * 36 + 16 + quad * 4];

    if (!LAST) {
        uint16_t* sO = (uint16_t*)(smem + 2304);
        #pragma unroll
        for (int ob = 0; ob < 4; ob++) {
            int oc = ob * 16 + row;
            float bias = brel[oc];
            f32x4 acc = {bias, bias, bias, bias};
            bf16x8 gh0 = *(const bf16x8*)&WgH[oc * 64 + kb];
            bf16x8 gh1 = *(const bf16x8*)&WgH[oc * 64 + 32 + kb];
            bf16x8 gl0 = *(const bf16x8*)&WgL[oc * 64 + kb];
            bf16x8 gl1 = *(const bf16x8*)&WgL[oc * 64 + 32 + kb];
            acc = __builtin_amdgcn_mfma_f32_16x16x32_bf16(ah0, gh0, acc, 0, 0, 0);
            acc = __builtin_amdgcn_mfma_f32_16x16x32_bf16(ah1, gh1, acc, 0, 0, 0);
            acc = __builtin_amdgcn_mfma_f32_16x16x32_bf16(ah0, gl0, acc, 0, 0, 0);
            acc = __builtin_amdgcn_mfma_f32_16x16x32_bf16(ah1, gl1, acc, 0, 0, 0);
            bf16x8 rh0 = *(const bf16x8*)&WrH[oc * 64 + kb];
            bf16x8 rh1 = *(const bf16x8*)&WrH[oc * 64 + 32 + kb];
            bf16x8 rl0 = *(const bf16x8*)&WrL[oc * 64 + kb];
            bf16x8 rl1 = *(const bf16x8*)&WrL[oc * 64 + 32 + kb];
            acc = __builtin_amdgcn_mfma_f32_16x16x32_bf16(hs0, rh0, acc, 0, 0, 0);
            acc = __builtin_amdgcn_mfma_f32_16x16x32_bf16(hs1, rh1, acc, 0, 0, 0);
            acc = __builtin_amdgcn_mfma_f32_16x16x32_bf16(hs0, rl0, acc, 0, 0, 0);
            acc = __builtin_amdgcn_mfma_f32_16x16x32_bf16(hs1, rl1, acc, 0, 0, 0);
            #pragma unroll
            for (int r = 0; r < 4; r++) {
                float v = acc[r] > 0.f ? acc[r] : 0.f;
                sO[(quad * 4 + r) * 68 + oc] = (uint16_t)rne_bf16(v);
            }
        }
        asm volatile("s_waitcnt lgkmcnt(0)" ::: "memory");
        __builtin_amdgcn_sched_barrier(0);
        const uint32_t* sOd = (const uint32_t*)sO;
        uint32_t* Hd = (uint32_t*)Hout;
        #pragma unroll
        for (int it = 0; it < 8; it++) {
            int idx = it * 64 + c;
            int nd = idx >> 5, col = idx & 31;
            Hd[(n0 + nd) * 32 + col] = sOd[nd * 34 + col];
        }
    } else {
        float pa[4] = {0.f, 0.f, 0.f, 0.f};
        float pr[4] = {0.f, 0.f, 0.f, 0.f};
        #pragma unroll
        for (int ob = 0; ob < 4; ob++) {
            int oc = ob * 16 + row;
            float bias = brel[oc];
            f32x4 acc = {bias, bias, bias, bias};
            bf16x8 gh0 = *(const bf16x8*)&WgH[oc * 64 + kb];
            bf16x8 gh1 = *(const bf16x8*)&WgH[oc * 64 + 32 + kb];
            bf16x8 gl0 = *(const bf16x8*)&WgL[oc * 64 + kb];
            bf16x8 gl1 = *(const bf16x8*)&WgL[oc * 64 + 32 + kb];
            acc = __builtin_amdgcn_mfma_f32_16x16x32_bf16(ah0, gh0, acc, 0, 0, 0);
            acc = __builtin_amdgcn_mfma_f32_16x16x32_bf16(ah1, gh1, acc, 0, 0, 0);
            acc = __builtin_amdgcn_mfma_f32_16x16x32_bf16(ah0, gl0, acc, 0, 0, 0);
            acc = __builtin_amdgcn_mfma_f32_16x16x32_bf16(ah1, gl1, acc, 0, 0, 0);
            bf16x8 rh0 = *(const bf16x8*)&WrH[oc * 64 + kb];
            bf16x8 rh1 = *(const bf16x8*)&WrH[oc * 64 + 32 + kb];
            bf16x8 rl0 = *(const bf16x8*)&WrL[oc * 64 + kb];
            bf16x8 rl1 = *(const bf16x8*)&WrL[oc * 64 + 32 + kb];
            acc = __builtin_amdgcn_mfma_f32_16x16x32_bf16(hs0, rh0, acc, 0, 0, 0);
            acc = __builtin_amdgcn_mfma_f32_16x16x32_bf16(hs1, rh1, acc, 0, 0, 0);
            acc = __builtin_amdgcn_mfma_f32_16x16x32_bf16(hs0, rl0, acc, 0, 0, 0);
            acc = __builtin_amdgcn_mfma_f32_16x16x32_bf16(hs1, rl1, acc, 0, 0, 0);
            float wlc = WrelL[oc], woc = WrootL[oc];
            #pragma unroll
            for (int r = 0; r < 4; r++) {
                float v = acc[r] > 0.f ? acc[r] : 0.f;
                pa[r] += v * wlc;
                pr[r] += v * woc;
            }
        }
        #pragma unroll
        for (int r = 0; r < 4; r++) {
            #pragma unroll
            for (int o = 8; o > 0; o >>= 1) {
                pa[r] += __shfl_down(pa[r], o, 16);
                pr[r] += __shfl_down(pr[r], o, 16);
            }
            if (row == 0) {
                int node = n0 + quad * 4 + r;
                sarr[node] = pa[r];
                rarr[node] = pr[r];
            }
        }
    }
}

// final edge pass: wave-per-4-nodes edge-parallel gather + shfl reduce
__global__ __launch_bounds__(256) void k_last(
        const int* __restrict__ offs, const int* __restrict__ ends,
        const uint32_t* __restrict__ pairs,
        const float* __restrict__ sarr, const float* __restrict__ rarr,
        const float* __restrict__ brelL, float* __restrict__ out) {
    int c = threadIdx.x & 63;
    int w = threadIdx.x >> 6;
    int blk16 = blockIdx.x * 16;
    float b0 = brelL[0];
    #pragma unroll
    for (int t = 0; t < 4; t++) {
        int node = blk16 + w * 4 + t;
        int b = offs[node], e = ends[node];
        float pp = 0.f;
        for (int j = b + c; j < e; j += 64) {
            uint32_t r = pairs[j];
            pp += __uint_as_float((r >> 17) << 16) * sarr[r & 0x1ffffu];
        }
        #pragma unroll
        for (int o = 32; o > 0; o >>= 1) pp += __shfl_down(pp, o, 64);
        if (c == 0) out[node] = pp + rarr[node] + b0;
    }
}

extern "C" void kernel_launch(void* const* d_in, const int* in_sizes, int n_in,
                              void* d_out, int out_size, void* d_ws, size_t ws_size,
                              hipStream_t stream) {
    const float* x        = (const float*)d_in[0];
    const int*   ei       = (const int*)d_in[1];
    const float* ew       = (const float*)d_in[2];
    const float* Wrel0    = (const float*)d_in[3];
    const float* brel0    = (const float*)d_in[4];
    const float* Wroot0   = (const float*)d_in[5];
    const float* Wrel_mid = (const float*)d_in[6];
    const float* brel_mid = (const float*)d_in[7];
    const float* Wroot_mid= (const float*)d_in[8];
    const float* WrelL    = (const float*)d_in[9];
    const float* brelL    = (const float*)d_in[10];
    const float* WrootL   = (const float*)d_in[11];
    float* out = (float*)d_out;

    const int* src  = ei;
    const int* dstp = ei + NE;

    char* w = (char*)d_ws;
    size_t o = 0;
    auto alloc = [&](size_t b) -> void* {
        void* r = (void*)(w + o);
        o += (b + 255) & ~(size_t)255;
        return r;
    };
    int*      offs  = (int*)alloc((size_t)NN * 4);
    int*      ends  = (int*)alloc((size_t)NN * 4);
    int*      bcur  = (int*)alloc((size_t)NBKT * 4);
    uint16_t* WgH   = (uint16_t*)alloc((size_t)3 * 4096 * 2);
    uint16_t* WgL   = (uint16_t*)alloc((size_t)3 * 4096 * 2);
    uint16_t* WrH   = (uint16_t*)alloc((size_t)3 * 4096 * 2);
    uint16_t* WrL   = (uint16_t*)alloc((size_t)3 * 4096 * 2);
    float*    sarr  = (float*)alloc((size_t)NN * 4);
    float*    rarr  = (float*)alloc((size_t)NN * 4);
    float2*   AX    = (float2*)alloc((size_t)NN * 8);            // 0.8 MB
    uint32_t* pairs = (uint32_t*)alloc((size_t)NBKT * CAP * 4);  // 12.8 MB padded
    uint16_t* HbA   = (uint16_t*)alloc((size_t)NN * HID * 2);    // 12.8 MB
    uint16_t* HbB   = (uint16_t*)alloc((size_t)NN * HID * 2);
    uint16_t* spare = (uint16_t*)alloc((size_t)NN * HID * 2);    // bpairs tail
    (void)spare;
    // bpairs (NBKT*CAP*8B = 25.6MB) aliases HbB+spare (contiguous; dead
    // before k_agg1 writes HbB)
    int2*  bpairs = (int2*)HbB;

    // weight split + bucket cursor init (one launch)
    k_wsplit<<<(3 * 4096 + 255) / 256, 256, 0, stream>>>(
        Wrel_mid, Wroot_mid, WgH, WgL, WrH, WrL, bcur);

    // CSR build (padded buckets)
    k_bpart<<<NTILE, 256, 0, stream>>>(src, dstp, ew, bcur, bpairs);
    k_bcsr<<<NBKT, 256, 0, stream>>>(bcur, bpairs, offs, ends, pairs);

    // layer 0: rank-2 state AX = (aggx, x)
    k_l0pre<<<NN / 16, 256, 0, stream>>>(offs, ends, pairs, x, AX);

    int nagg = NN / 16;   // 6250 one-wave blocks, 16 nodes each
    // mid layer 1 (rank-2 input): AX -> h2 rows (weights idx 0)
    k_agg1<<<nagg, 64, 0, stream>>>(
        offs, ends, pairs, AX, Wrel0, brel0, Wroot0,
        WgH, WgL, WrH, WrL, brel_mid, HbB);
    // mid layer 2: h2 -> h3 (weights idx 1)
    k_aggfused<false><<<nagg, 64, 0, stream>>>(
        offs, ends, pairs, HbB,
        WgH + 4096, WgL + 4096, WrH + 4096, WrL + 4096, brel_mid + HID,
        HbA, WrelL, WrootL, sarr, rarr);
    // mid layer 3 (LAST): h3 -> sarr/rarr (weights idx 2)
    k_aggfused<true><<<nagg, 64, 0, stream>>>(
        offs, ends, pairs, HbA,
        WgH + 2 * 4096, WgL + 2 * 4096, WrH + 2 * 4096, WrL + 2 * 4096,
        brel_mid + 2 * HID,
        HbB, WrelL, WrootL, sarr, rarr);

    // final edge pass on scalars
    k_last<<<NN / 16, 256, 0, stream>>>(offs, ends, pairs, sarr, rarr, brelL, out);
}

// Round 13
// 280.677 us; speedup vs baseline: 1.1308x; 1.0244x over previous
//
#include <hip/hip_runtime.h>
#include <stdint.h>

// GraphConv x5 on MI355X — round 32.
// vs round 31 (287.5us; k_agg1 55us — traffic gone (FETCH 8.7MB) but
// reconstruction VALU-bound: 48 bpermute + ~480 VALU/iter, ~8 instr/edge):
// (1) redistribute (a,x) via LDS SoA — lane writes its edge once (2x
// ds_write_b32), reads 8 contiguous values per chunk (2x ds_read_b128 per
// array; quad-broadcast, conflict-free): 32 bpermutes -> 10 DS ops.
// (2) v_cvt_pk_bf16_f32 (RNE, 1 instr / 2 elems) replaces the 4-op integer
// rne+pack: h-compute ~480 -> ~224 VALU/iter. A-frag masks unchanged.
// Everything else identical to round 31.

#define NN 100000
#define NE 1600000
#define HID 64
#define NBKT 391            // ceil(NN/256), bucket = dst >> 8
#define CAP 8192            // padded bucket capacity (mean 4092, +64 sigma)
#define PMAX (NBKT * CAP)
#define TILE 4096
#define EPT 16              // TILE / 256
#define NTILE ((NE + TILE - 1) / TILE)   // 391

typedef __attribute__((ext_vector_type(8))) short bf16x8;
typedef __attribute__((ext_vector_type(4))) float f32x4;
typedef __attribute__((ext_vector_type(2))) unsigned int u32x2;
typedef __attribute__((ext_vector_type(4))) unsigned int u32x4;

__device__ __forceinline__ uint32_t rne_bf16(float v) {
    uint32_t u = __float_as_uint(v);
    return (u + 0x7fffu + ((u >> 16) & 1u)) >> 16;
}

// ---------------- CSR build ----------------

// tile-local LDS counting sort + coalesced segment write-out
__global__ __launch_bounds__(256) void k_bpart(const int* __restrict__ src,
                                               const int* __restrict__ dst,
                                               const float* __restrict__ w,
                                               int* __restrict__ bcur,
                                               int2* __restrict__ bpairs) {
    __shared__ int  hcnt[NBKT];      // count, then cursor
    __shared__ int  hoff[NBKT];      // local exclusive offset
    __shared__ int  hadj[NBKT];      // global base - local offset
    __shared__ int  sc0[512];
    __shared__ int  sc1[512];
    __shared__ int2 sT[TILE];        // 32 KB staged tile (bucket-sorted)
    __shared__ int  sAdj[TILE];      // 16 KB per-slot global adjust
    int tile0 = blockIdx.x * TILE;
    int t = threadIdx.x;
    for (int i = t; i < NBKT; i += 256) hcnt[i] = 0;
    __syncthreads();

    int   pk[EPT];
    int   bk[EPT];
    float wv[EPT];
    #pragma unroll
    for (int k = 0; k < EPT; k++) {
        int e = tile0 + t + k * 256;
        if (e < NE) {
            int d = dst[e];
            int b = d >> 8;
            pk[k] = (src[e] << 8) | (d & 255);
            wv[k] = w[e];
            bk[k] = b;
            atomicAdd(&hcnt[b], 1);
        } else {
            bk[k] = -1;
        }
    }
    __syncthreads();

    // inclusive scan of hcnt over 512 (padded) with ping-pong buffers
    sc0[t]       = (t < NBKT) ? hcnt[t] : 0;
    sc0[t + 256] = (t + 256 < NBKT) ? hcnt[t + 256] : 0;
    __syncthreads();
    int* cur = sc0;
    int* oth = sc1;
    for (int off = 1; off < 512; off <<= 1) {
        int v0 = cur[t]       + ((t       >= off) ? cur[t - off]       : 0);
        int v1 = cur[t + 256] + ((t + 256 >= off) ? cur[t + 256 - off] : 0);
        oth[t] = v0;
        oth[t + 256] = v1;
        __syncthreads();
        int* tmp = cur; cur = oth; oth = tmp;
    }
    for (int i = t; i < NBKT; i += 256) {
        int c = hcnt[i];
        int excl = cur[i] - c;
        hoff[i] = excl;
        int gbase = c ? atomicAdd(&bcur[i], c) : 0;
        hadj[i] = gbase - excl;
        hcnt[i] = 0;                 // reuse as local cursor
    }
    __syncthreads();

    // scatter into LDS (bucket-sorted order)
    #pragma unroll
    for (int k = 0; k < EPT; k++) {
        if (bk[k] >= 0) {
            int b = bk[k];
            int pos = hoff[b] + atomicAdd(&hcnt[b], 1);
            sT[pos] = make_int2(pk[k], __float_as_int(wv[k]));
            sAdj[pos] = hadj[b];
        }
    }
    __syncthreads();

    // linear write-out: consecutive slots in a bucket run -> consecutive
    // global addresses (coalesced bursts)
    int n = NE - tile0; if (n > TILE) n = TILE;
    for (int j = t; j < n; j += 256)
        bpairs[sAdj[j] + j] = sT[j];
}

// one block per bucket: stage bucket in LDS, then LDS counting sort.
__global__ __launch_bounds__(256) void k_bcsr(const int* __restrict__ bcur,
                                              const int2* __restrict__ bpairs,
                                              int* __restrict__ offs,
                                              int* __restrict__ ends,
                                              uint32_t* __restrict__ pairs) {
    __shared__ int2 sE[CAP];        // 64 KB bucket stage
    __shared__ int cnt[256];
    __shared__ int scn[256];
    __shared__ int cur[256];
    int k = blockIdx.x, t = threadIdx.x;
    int base = k * CAP;
    int scnt = bcur[k] - base;
    cnt[t] = 0;
    __syncthreads();
    for (int j = t; j < scnt; j += 256) {
        int2 q = bpairs[base + j];
        sE[j] = q;
        atomicAdd(&cnt[q.x & 255], 1);
    }
    __syncthreads();
    int v = cnt[t], acc = v;
    scn[t] = v;
    __syncthreads();
    for (int off = 1; off < 256; off <<= 1) {
        int u = (t >= off) ? scn[t - off] : 0;
        __syncthreads();
        acc += u;
        scn[t] = acc;
        __syncthreads();
    }
    int excl = acc - v;
    cur[t] = excl;
    int d = (k << 8) + t;
    if (d < NN) {
        offs[d] = base + excl;
        ends[d] = base + excl + v;
    }
    __syncthreads();
    for (int j = t; j < scnt; j += 256) {
        int2 q = sE[j];
        int pos = base + atomicAdd(&cur[q.x & 255], 1);
        uint32_t wb = rne_bf16(__int_as_float(q.y)) & 0x7fffu;   // w >= 0
        pairs[pos] = (wb << 17) | (uint32_t)(q.x >> 8);
    }
}

// ---------------- weight hi/lo split (+ bucket cursor init) ----------------

__global__ __launch_bounds__(256) void k_wsplit(const float* __restrict__ Wrel_mid,
                                                const float* __restrict__ Wroot_mid,
                                                uint16_t* __restrict__ WgH,
                                                uint16_t* __restrict__ WgL,
                                                uint16_t* __restrict__ WrH,
                                                uint16_t* __restrict__ WrL,
                                                int* __restrict__ bcur) {
    int i = blockIdx.x * blockDim.x + threadIdx.x;
    if (i < NBKT) bcur[i] = i * CAP;
    if (i >= 3 * 4096) return;
    float a = Wrel_mid[i];
    uint32_t ah = rne_bf16(a);
    float al = a - __uint_as_float(ah << 16);
    WgH[i] = (uint16_t)ah;
    WgL[i] = (uint16_t)rne_bf16(al);
    float b = Wroot_mid[i];
    uint32_t bh = rne_bf16(b);
    float bl = b - __uint_as_float(bh << 16);
    WrH[i] = (uint16_t)bh;
    WrL[i] = (uint16_t)rne_bf16(bl);
}

// ---------------- layers ----------------

// layer 0: edge-parallel aggregation (4 nodes/wave, shfl reduce); writes
// ONLY the rank-2 state AX[node] = (aggx, x).
__global__ __launch_bounds__(256) void k_l0pre(
        const int* __restrict__ offs, const int* __restrict__ ends,
        const uint32_t* __restrict__ pairs, const float* __restrict__ x,
        float2* __restrict__ AX) {
    int c = threadIdx.x & 63;
    int w = threadIdx.x >> 6;
    int blk16 = blockIdx.x * 16;
    #pragma unroll
    for (int t = 0; t < 4; t++) {
        int node = blk16 + w * 4 + t;
        int b = offs[node], e = ends[node];
        float pp = 0.f;
        for (int j = b + c; j < e; j += 64) {
            uint32_t r = pairs[j];
            pp += __uint_as_float((r >> 17) << 16) * x[r & 0x1ffffu];
        }
        for (int o = 32; o > 0; o >>= 1) pp += __shfl_down(pp, o, 64);
        if (c == 0) AX[node] = make_float2(pp, x[node]);
    }
}

// transpose-read, byte-addressed: column = addr bits[6:3], subtile = the
// 128B-aligned base; lane reads bytes (addr&~127) + ((addr>>3)&15)*2 + 32*j
#define TRRA(dst, off) \
    asm volatile("ds_read_b64_tr_b16 %0, %1 offset:" #off \
                 : "=v"(dst) : "v"(trbA))
#define TRRB(dst, off) \
    asm volatile("ds_read_b64_tr_b16 %0, %1 offset:" #off \
                 : "=v"(dst) : "v"(trbB))

// Mid layer 1 (rank-2 input): gather 8B (aggx,x) per edge; redistribute
// via LDS SoA (abuf/xbuf); h1 B-fragments reconstructed with packed
// cvt_pk_bf16; MFMA consume; standard epilogue -> h2 rows.
__global__ __launch_bounds__(64, 4) void k_agg1(
        const int* __restrict__ offs, const int* __restrict__ ends,
        const uint32_t* __restrict__ pairs,
        const float2* __restrict__ AX,
        const float* __restrict__ Wrel0, const float* __restrict__ brel0,
        const float* __restrict__ Wroot0,
        const uint16_t* __restrict__ WgH, const uint16_t* __restrict__ WgL,
        const uint16_t* __restrict__ WrH, const uint16_t* __restrict__ WrL,
        const float* __restrict__ brel,
        uint16_t* __restrict__ Hout) {
    // [0,256) abuf, [256,512) xbuf during the loop; epilogue overlays with
    // sH(2304B) at 0 and sO(2176B) at 2304.
    __shared__ __align__(128) char smem[4608];
    int c = threadIdx.x;                  // 0..63
    int n0 = blockIdx.x * 16;
    int row = c & 15;
    int quad = c >> 4;
    int kq = quad * 8;

    int myNode = n0 + row;
    int blo = offs[myNode];
    int bhi = ends[myNode];
    uint32_t wid = (uint32_t)(bhi - blo);
    int start  = __builtin_amdgcn_readlane(blo, 0);
    int finish = __builtin_amdgcn_readlane(bhi, 15);

    // per-lane B-column weights (col = nb*16 + row)
    float wrc[4], brc[4], woc[4];
    #pragma unroll
    for (int nb = 0; nb < 4; nb++) {
        int col = nb * 16 + row;
        wrc[nb] = Wrel0[col]; brc[nb] = brel0[col]; woc[nb] = Wroot0[col];
    }

    f32x4 acc16[4];
    #pragma unroll
    for (int nb = 0; nb < 4; nb++) acc16[nb] = f32x4{0.f, 0.f, 0.f, 0.f};

    float* abuf = (float*)smem;
    float* xbuf = (float*)(smem + 256);

    int j0 = start + c; if (j0 > PMAX - 1) j0 = PMAX - 1;
    uint32_t praw = pairs[j0];
    uint32_t p = (start + c < finish) ? praw : 0;

    for (int cb = start; cb < finish; cb += 64) {
        int jn = cb + 64 + c; if (jn > PMAX - 1) jn = PMAX - 1;
        uint32_t pr2 = pairs[jn];
        float2 ax = AX[p & 0x1ffffu];     // 8B gather (L2-resident table)
        // A fragments (masked weights) under the load shadow
        uint32_t mA[8], mB[8];
        int dbA = cb + kq - blo;
        int dbB = cb + 32 + kq - blo;
        #pragma unroll
        for (int q = 0; q < 8; q++) {
            uint32_t rq = (uint32_t)__builtin_amdgcn_ds_bpermute(
                (kq + q) * 4, (int)p);
            mA[q] = ((uint32_t)(dbA + q) < wid) ? (rq >> 17) : 0u;
        }
        #pragma unroll
        for (int q = 0; q < 8; q++) {
            uint32_t rq = (uint32_t)__builtin_amdgcn_ds_bpermute(
                (32 + kq + q) * 4, (int)p);
            mB[q] = ((uint32_t)(dbB + q) < wid) ? (rq >> 17) : 0u;
        }
        u32x4 aav = { mA[0] | (mA[1] << 16), mA[2] | (mA[3] << 16),
                      mA[4] | (mA[5] << 16), mA[6] | (mA[7] << 16) };
        u32x4 abv = { mB[0] | (mB[1] << 16), mB[2] | (mB[3] << 16),
                      mB[4] | (mB[5] << 16), mB[6] | (mB[7] << 16) };
        bf16x8 afA = __builtin_bit_cast(bf16x8, aav);
        bf16x8 afB = __builtin_bit_cast(bf16x8, abv);
        asm volatile("s_waitcnt vmcnt(0)" ::: "memory");  // ax + pr2 ready
        // SoA stage: lane writes its edge's (a,x)
        abuf[c] = ax.x;
        xbuf[c] = ax.y;
        asm volatile("s_waitcnt lgkmcnt(0)" ::: "memory");
        __builtin_amdgcn_sched_barrier(0);
        #pragma unroll
        for (int s = 0; s < 2; s++) {
            // lane's 8 edges are contiguous: 2x b128 per array
            f32x4 aL = *(const f32x4*)(smem + s * 128 + kq * 4);
            f32x4 aH = *(const f32x4*)(smem + s * 128 + kq * 4 + 16);
            f32x4 xL = *(const f32x4*)(smem + 256 + s * 128 + kq * 4);
            f32x4 xH = *(const f32x4*)(smem + 256 + s * 128 + kq * 4 + 16);
            asm volatile("s_waitcnt lgkmcnt(0)" ::: "memory");
            __builtin_amdgcn_sched_barrier(0);
            float ar[8], xr[8];
            #pragma unroll
            for (int q = 0; q < 4; q++) {
                ar[q] = aL[q]; ar[q + 4] = aH[q];
                xr[q] = xL[q]; xr[q + 4] = xH[q];
            }
            bf16x8 af = s ? afB : afA;
            #pragma unroll
            for (int nb = 0; nb < 4; nb++) {
                float wr = wrc[nb], br = brc[nb], wo = woc[nb];
                uint32_t bw[4];
                #pragma unroll
                for (int jj = 0; jj < 4; jj++) {
                    float h0 = fmaf(ar[2 * jj], wr, fmaf(xr[2 * jj], wo, br));
                    float h1 = fmaf(ar[2 * jj + 1], wr,
                                    fmaf(xr[2 * jj + 1], wo, br));
                    h0 = h0 > 0.f ? h0 : 0.f;
                    h1 = h1 > 0.f ? h1 : 0.f;
                    asm("v_cvt_pk_bf16_f32 %0, %1, %2"
                        : "=v"(bw[jj]) : "v"(h0), "v"(h1));
                }
                u32x4 bb = { bw[0], bw[1], bw[2], bw[3] };
                acc16[nb] = __builtin_amdgcn_mfma_f32_16x16x32_bf16(
                    af, __builtin_bit_cast(bf16x8, bb), acc16[nb], 0, 0, 0);
            }
        }
        p = (cb + 64 + c < finish) ? pr2 : 0;
    }

    // ---- epilogue: h2 = relu(Wrel1.agg + Wroot1.h1_self + brel1) ----
    // h1_self fragments reconstructed from AX[n0+row]
    float2 axs = AX[n0 + row];
    uint32_t e0[8], e1[8];
    #pragma unroll
    for (int q = 0; q < 8; q++) {
        int k0 = kq + q;
        float h = axs.x * Wrel0[k0] + brel0[k0] + axs.y * Wroot0[k0];
        h = h > 0.f ? h : 0.f;
        e0[q] = rne_bf16(h);
        int k1 = 32 + kq + q;
        float h2 = axs.x * Wrel0[k1] + brel0[k1] + axs.y * Wroot0[k1];
        h2 = h2 > 0.f ? h2 : 0.f;
        e1[q] = rne_bf16(h2);
    }
    u32x4 hv0 = { e0[0] | (e0[1] << 16), e0[2] | (e0[3] << 16),
                  e0[4] | (e0[5] << 16), e0[6] | (e0[7] << 16) };
    u32x4 hv1 = { e1[0] | (e1[1] << 16), e1[2] | (e1[3] << 16),
                  e1[4] | (e1[5] << 16), e1[6] | (e1[7] << 16) };
    bf16x8 hs0 = __builtin_bit_cast(bf16x8, hv0);
    bf16x8 hs1 = __builtin_bit_cast(bf16x8, hv1);

    // pack agg (NO relu) -> sH (overlays abuf/xbuf, now dead)
    uint32_t* sHw = (uint32_t*)smem;
    #pragma unroll
    for (int t = 0; t < 4; t++) {
        #pragma unroll
        for (int nb = 0; nb < 4; nb++) {
            uint32_t hb = rne_bf16(acc16[nb][t]);
            uint32_t pn2 = (uint32_t)__shfl_xor((int)hb, 1, 64);
            if (!(c & 1))
                sHw[(quad * 4 + t) * 36 + nb * 8 + (row >> 1)]
                    = hb | (pn2 << 16);
        }
    }
    asm volatile("s_waitcnt lgkmcnt(0)" ::: "memory");
    __builtin_amdgcn_sched_barrier(0);
    int kb = quad * 8;
    bf16x8 ah0 = *(const bf16x8*)&sHw[row * 36 + quad * 4];
    bf16x8 ah1 = *(const bf16x8*)&sHw[row * 36 + 16 + quad * 4];

    uint16_t* sO = (uint16_t*)(smem + 2304);
    #pragma unroll
    for (int ob = 0; ob < 4; ob++) {
        int oc = ob * 16 + row;
        float bias = brel[oc];
        f32x4 acc = {bias, bias, bias, bias};
        bf16x8 gh0 = *(const bf16x8*)&WgH[oc * 64 + kb];
        bf16x8 gh1 = *(const bf16x8*)&WgH[oc * 64 + 32 + kb];
        bf16x8 gl0 = *(const bf16x8*)&WgL[oc * 64 + kb];
        bf16x8 gl1 = *(const bf16x8*)&WgL[oc * 64 + 32 + kb];
        acc = __builtin_amdgcn_mfma_f32_16x16x32_bf16(ah0, gh0, acc, 0, 0, 0);
        acc = __builtin_amdgcn_mfma_f32_16x16x32_bf16(ah1, gh1, acc, 0, 0, 0);
        acc = __builtin_amdgcn_mfma_f32_16x16x32_bf16(ah0, gl0, acc, 0, 0, 0);
        acc = __builtin_amdgcn_mfma_f32_16x16x32_bf16(ah1, gl1, acc, 0, 0, 0);
        bf16x8 rh0 = *(const bf16x8*)&WrH[oc * 64 + kb];
        bf16x8 rh1 = *(const bf16x8*)&WrH[oc * 64 + 32 + kb];
        bf16x8 rl0 = *(const bf16x8*)&WrL[oc * 64 + kb];
        bf16x8 rl1 = *(const bf16x8*)&WrL[oc * 64 + 32 + kb];
        acc = __builtin_amdgcn_mfma_f32_16x16x32_bf16(hs0, rh0, acc, 0, 0, 0);
        acc = __builtin_amdgcn_mfma_f32_16x16x32_bf16(hs1, rh1, acc, 0, 0, 0);
        acc = __builtin_amdgcn_mfma_f32_16x16x32_bf16(hs0, rl0, acc, 0, 0, 0);
        acc = __builtin_amdgcn_mfma_f32_16x16x32_bf16(hs1, rl1, acc, 0, 0, 0);
        #pragma unroll
        for (int r = 0; r < 4; r++) {
            float v = acc[r] > 0.f ? acc[r] : 0.f;
            sO[(quad * 4 + r) * 68 + oc] = (uint16_t)rne_bf16(v);
        }
    }
    asm volatile("s_waitcnt lgkmcnt(0)" ::: "memory");
    __builtin_amdgcn_sched_barrier(0);
    const uint32_t* sOd = (const uint32_t*)sO;
    uint32_t* Hd = (uint32_t*)Hout;
    #pragma unroll
    for (int it = 0; it < 8; it++) {
        int idx = it * 64 + c;
        int nd = idx >> 5, col = idx & 31;
        Hd[(n0 + nd) * 32 + col] = sOd[nd * 34 + col];
    }
}

// Mid layer (rank-64): gather h rows (r28 schedule), agg via MFMA
// (C-init 0), epilogue h_next = relu(Wrel.agg + Wroot.h_self + brel).
// LAST: epilogue then width-16 shfl dots with WrelL/WrootL -> sarr/rarr.
template <bool LAST>
__global__ __launch_bounds__(64, 5) void k_aggfused(
        const int* __restrict__ offs, const int* __restrict__ ends,
        const uint32_t* __restrict__ pairs,
        const uint16_t* __restrict__ Hb,
        const uint16_t* __restrict__ WgH, const uint16_t* __restrict__ WgL,
        const uint16_t* __restrict__ WrH, const uint16_t* __restrict__ WrL,
        const float* __restrict__ brel,
        uint16_t* __restrict__ Hout,
        const float* __restrict__ WrelL, const float* __restrict__ WrootL,
        float* __restrict__ sarr, float* __restrict__ rarr) {
    __shared__ __align__(128) char smem[8192];
    int c = threadIdx.x;                  // 0..63
    int n0 = blockIdx.x * 16;             // wave owns nodes [n0, n0+16)

    int myNode = n0 + (c & 15);
    int blo = offs[myNode];
    int bhi = ends[myNode];
    uint32_t wid = (uint32_t)(bhi - blo);
    int start  = __builtin_amdgcn_readlane(blo, 0);
    int finish = __builtin_amdgcn_readlane(bhi, 15);

    int kq = (c >> 4) * 8;                // MFMA k-base for this quad
    int eprm  = ((c >> 5) << 2) | ((c >> 1) & 3);
    int lbyte = ((c >> 3) & 3) * 32 + (c & 1) * 16;
    char* stg = smem;                     // chunk A: stg, chunk B: +4096
    uint32_t stgOff = (uint32_t)(uintptr_t)
        (__attribute__((address_space(3))) char*)stg;
    uint32_t trbA = stgOff + ((uint32_t)(c >> 4) << 10)
                          + ((uint32_t)(c & 15) << 3);
    uint32_t trbB = trbA + 4096;

    f32x4 acc16[4];
    #pragma unroll
    for (int nb = 0; nb < 4; nb++) acc16[nb] = f32x4{0.f, 0.f, 0.f, 0.f};

    const char* gbase = (const char*)Hb;
    int j0 = start + c; if (j0 > PMAX - 1) j0 = PMAX - 1;
    uint32_t praw = pairs[j0];
    uint32_t p = (start + c < finish) ? praw : 0;

    for (int cb = start; cb < finish; cb += 64) {
        int jn = cb + 64 + c; if (jn > PMAX - 1) jn = PMAX - 1;
        uint32_t pr2 = pairs[jn];                               // vmem 1
        #pragma unroll
        for (int i = 0; i < 4; i++) {                           // vmem 2-5
            uint32_t r = (uint32_t)__builtin_amdgcn_ds_bpermute(
                (eprm + i * 8) * 4, (int)p);
            uint32_t voff = ((r & 0x1ffffu) << 7) + (uint32_t)lbyte;
            __builtin_amdgcn_global_load_lds(
                (const __attribute__((address_space(1))) void*)(gbase + voff),
                (__attribute__((address_space(3))) void*)(stg + i * 1024),
                16, 0, 0);
        }
        #pragma unroll
        for (int i = 0; i < 4; i++) {                           // vmem 6-9
            uint32_t r = (uint32_t)__builtin_amdgcn_ds_bpermute(
                (32 + eprm + i * 8) * 4, (int)p);
            uint32_t voff = ((r & 0x1ffffu) << 7) + (uint32_t)lbyte;
            __builtin_amdgcn_global_load_lds(
                (const __attribute__((address_space(1))) void*)(gbase + voff),
                (__attribute__((address_space(3))) void*)(stg + 4096 + i * 1024),
                16, 0, 0);
        }
        uint32_t mA[8], mB[8];
        int dbA = cb + kq - blo;
        int dbB = cb + 32 + kq - blo;
        #pragma unroll
        for (int q = 0; q < 8; q++) {
            uint32_t rq = (uint32_t)__builtin_amdgcn_ds_bpermute(
                (kq + q) * 4, (int)p);
            mA[q] = ((uint32_t)(dbA + q) < wid) ? (rq >> 17) : 0u;
        }
        #pragma unroll
        for (int q = 0; q < 8; q++) {
            uint32_t rq = (uint32_t)__builtin_amdgcn_ds_bpermute(
                (32 + kq + q) * 4, (int)p);
            mB[q] = ((uint32_t)(dbB + q) < wid) ? (rq >> 17) : 0u;
        }
        u32x4 aav = { mA[0] | (mA[1] << 16), mA[2] | (mA[3] << 16),
                      mA[4] | (mA[5] << 16), mA[6] | (mA[7] << 16) };
        u32x4 abv = { mB[0] | (mB[1] << 16), mB[2] | (mB[3] << 16),
                      mB[4] | (mB[5] << 16), mB[6] | (mB[7] << 16) };
        bf16x8 afA = __builtin_bit_cast(bf16x8, aav);
        bf16x8 afB = __builtin_bit_cast(bf16x8, abv);
        asm volatile("s_waitcnt vmcnt(4)" ::: "memory");
        {
            u32x2 tb0, tb1, tb2, tb3, tb4, tb5, tb6, tb7;
            TRRA(tb0, 0);   TRRA(tb1, 512);
            TRRA(tb2, 128); TRRA(tb3, 640);
            TRRA(tb4, 256); TRRA(tb5, 768);
            TRRA(tb6, 384); TRRA(tb7, 896);
            asm volatile("s_waitcnt lgkmcnt(0)" ::: "memory");
            __builtin_amdgcn_sched_barrier(0);
            u32x4 bb0 = { tb0.x, tb0.y, tb1.x, tb1.y };
            acc16[0] = __builtin_amdgcn_mfma_f32_16x16x32_bf16(
                afA, __builtin_bit_cast(bf16x8, bb0), acc16[0], 0, 0, 0);
            u32x4 bb1 = { tb2.x, tb2.y, tb3.x, tb3.y };
            acc16[1] = __builtin_amdgcn_mfma_f32_16x16x32_bf16(
                afA, __builtin_bit_cast(bf16x8, bb1), acc16[1], 0, 0, 0);
            u32x4 bb2 = { tb4.x, tb4.y, tb5.x, tb5.y };
            acc16[2] = __builtin_amdgcn_mfma_f32_16x16x32_bf16(
                afA, __builtin_bit_cast(bf16x8, bb2), acc16[2], 0, 0, 0);
            u32x4 bb3 = { tb6.x, tb6.y, tb7.x, tb7.y };
            acc16[3] = __builtin_amdgcn_mfma_f32_16x16x32_bf16(
                afA, __builtin_bit_cast(bf16x8, bb3), acc16[3], 0, 0, 0);
        }
        asm volatile("s_waitcnt vmcnt(0)" ::: "memory");
        {
            u32x2 tb0, tb1, tb2, tb3, tb4, tb5, tb6, tb7;
            TRRB(tb0, 0);   TRRB(tb1, 512);
            TRRB(tb2, 128); TRRB(tb3, 640);
            TRRB(tb4, 256); TRRB(tb5, 768);
            TRRB(tb6, 384); TRRB(tb7, 896);
            asm volatile("s_waitcnt lgkmcnt(0)" ::: "memory");
            __builtin_amdgcn_sched_barrier(0);
            u32x4 bb0 = { tb0.x, tb0.y, tb1.x, tb1.y };
            acc16[0] = __builtin_amdgcn_mfma_f32_16x16x32_bf16(
                afB, __builtin_bit_cast(bf16x8, bb0), acc16[0], 0, 0, 0);
            u32x4 bb1 = { tb2.x, tb2.y, tb3.x, tb3.y };
            acc16[1] = __builtin_amdgcn_mfma_f32_16x16x32_bf16(
                afB, __builtin_bit_cast(bf16x8, bb1), acc16[1], 0, 0, 0);
            u32x4 bb2 = { tb4.x, tb4.y, tb5.x, tb5.y };
            acc16[2] = __builtin_amdgcn_mfma_f32_16x16x32_bf16(
                afB, __builtin_bit_cast(bf16x8, bb2), acc16[2], 0, 0, 0);
            u32x4 bb3 = { tb6.x, tb6.y, tb7.x, tb7.y };
            acc16[3] = __builtin_amdgcn_mfma_f32_16x16x32_bf16(
                afB, __builtin_bit_cast(bf16x8, bb3), acc16[3], 0, 0, 0);
        }
        p = (cb + 64 + c < finish) ? pr2 : 0;
    }
    asm volatile("s_waitcnt vmcnt(0)" ::: "memory");

    // ---- shared epilogue: h' = Wrel.agg + Wroot.h_self + brel ----
    int row = c & 15;
    int quad = c >> 4;
    int kb = quad * 8;
    bf16x8 hs0 = *(const bf16x8*)&Hb[(n0 + row) * 64 + kb];
    bf16x8 hs1 = *(const bf16x8*)&Hb[(n0 + row) * 64 + 32 + kb];
    uint32_t* sHw = (uint32_t*)smem;
    #pragma unroll
    for (int t = 0; t < 4; t++) {
        #pragma unroll
        for (int nb = 0; nb < 4; nb++) {
            uint32_t hb = rne_bf16(acc16[nb][t]);
            uint32_t pn2 = (uint32_t)__shfl_xor((int)hb, 1, 64);
            if (!(c & 1))
                sHw[(quad * 4 + t) * 36 + nb * 8 + (row >> 1)]
                    = hb | (pn2 << 16);
        }
    }
    asm volatile("s_waitcnt lgkmcnt(0)" ::: "memory");
    __builtin_amdgcn_sched_barrier(0);
    bf16x8 ah0 = *(const bf16x8*)&sHw[row * 36 + quad * 4];
    bf16x8 ah1 = *(const bf16x8*)&sHw[row * 36 + 16 + quad * 4];

    if (!LAST) {
        uint16_t* sO = (uint16_t*)(smem + 2304);
        #pragma unroll
        for (int ob = 0; ob < 4; ob++) {
            int oc = ob * 16 + row;
            float bias = brel[oc];
            f32x4 acc = {bias, bias, bias, bias};
            bf16x8 gh0 = *(const bf16x8*)&WgH[oc * 64 + kb];
            bf16x8 gh1 = *(const bf16x8*)&WgH[oc * 64 + 32 + kb];
            bf16x8 gl0 = *(const bf16x8*)&WgL[oc * 64 + kb];
            bf16x8 gl1 = *(const bf16x8*)&WgL[oc * 64 + 32 + kb];
            acc = __builtin_amdgcn_mfma_f32_16x16x32_bf16(ah0, gh0, acc, 0, 0, 0);
            acc = __builtin_amdgcn_mfma_f32_16x16x32_bf16(ah1, gh1, acc, 0, 0, 0);
            acc = __builtin_amdgcn_mfma_f32_16x16x32_bf16(ah0, gl0, acc, 0, 0, 0);
            acc = __builtin_amdgcn_mfma_f32_16x16x32_bf16(ah1, gl1, acc, 0, 0, 0);
            bf16x8 rh0 = *(const bf16x8*)&WrH[oc * 64 + kb];
            bf16x8 rh1 = *(const bf16x8*)&WrH[oc * 64 + 32 + kb];
            bf16x8 rl0 = *(const bf16x8*)&WrL[oc * 64 + kb];
            bf16x8 rl1 = *(const bf16x8*)&WrL[oc * 64 + 32 + kb];
            acc = __builtin_amdgcn_mfma_f32_16x16x32_bf16(hs0, rh0, acc, 0, 0, 0);
            acc = __builtin_amdgcn_mfma_f32_16x16x32_bf16(hs1, rh1, acc, 0, 0, 0);
            acc = __builtin_amdgcn_mfma_f32_16x16x32_bf16(hs0, rl0, acc, 0, 0, 0);
            acc = __builtin_amdgcn_mfma_f32_16x16x32_bf16(hs1, rl1, acc, 0, 0, 0);
            #pragma unroll
            for (int r = 0; r < 4; r++) {
                float v = acc[r] > 0.f ? acc[r] : 0.f;
                sO[(quad * 4 + r) * 68 + oc] = (uint16_t)rne_bf16(v);
            }
        }
        asm volatile("s_waitcnt lgkmcnt(0)" ::: "memory");
        __builtin_amdgcn_sched_barrier(0);
        const uint32_t* sOd = (const uint32_t*)sO;
        uint32_t* Hd = (uint32_t*)Hout;
        #pragma unroll
        for (int it = 0; it < 8; it++) {
            int idx = it * 64 + c;
            int nd = idx >> 5, col = idx & 31;
            Hd[(n0 + nd) * 32 + col] = sOd[nd * 34 + col];
        }
    } else {
        float pa[4] = {0.f, 0.f, 0.f, 0.f};
        float pr[4] = {0.f, 0.f, 0.f, 0.f};
        #pragma unroll
        for (int ob = 0; ob < 4; ob++) {
            int oc = ob * 16 + row;
            float bias = brel[oc];
            f32x4 acc = {bias, bias, bias, bias};
            bf16x8 gh0 = *(const bf16x8*)&WgH[oc * 64 + kb];
            bf16x8 gh1 = *(const bf16x8*)&WgH[oc * 64 + 32 + kb];
            bf16x8 gl0 = *(const bf16x8*)&WgL[oc * 64 + kb];
            bf16x8 gl1 = *(const bf16x8*)&WgL[oc * 64 + 32 + kb];
            acc = __builtin_amdgcn_mfma_f32_16x16x32_bf16(ah0, gh0, acc, 0, 0, 0);
            acc = __builtin_amdgcn_mfma_f32_16x16x32_bf16(ah1, gh1, acc, 0, 0, 0);
            acc = __builtin_amdgcn_mfma_f32_16x16x32_bf16(ah0, gl0, acc, 0, 0, 0);
            acc = __builtin_amdgcn_mfma_f32_16x16x32_bf16(ah1, gl1, acc, 0, 0, 0);
            bf16x8 rh0 = *(const bf16x8*)&WrH[oc * 64 + kb];
            bf16x8 rh1 = *(const bf16x8*)&WrH[oc * 64 + 32 + kb];
            bf16x8 rl0 = *(const bf16x8*)&WrL[oc * 64 + kb];
            bf16x8 rl1 = *(const bf16x8*)&WrL[oc * 64 + 32 + kb];
            acc = __builtin_amdgcn_mfma_f32_16x16x32_bf16(hs0, rh0, acc, 0, 0, 0);
            acc = __builtin_amdgcn_mfma_f32_16x16x32_bf16(hs1, rh1, acc, 0, 0, 0);
            acc = __builtin_amdgcn_mfma_f32_16x16x32_bf16(hs0, rl0, acc, 0, 0, 0);
            acc = __builtin_amdgcn_mfma_f32_16x16x32_bf16(hs1, rl1, acc, 0, 0, 0);
            float wlc = WrelL[oc], woc = WrootL[oc];
            #pragma unroll
            for (int r = 0; r < 4; r++) {
                float v = acc[r] > 0.f ? acc[r] : 0.f;
                pa[r] += v * wlc;
                pr[r] += v * woc;
            }
        }
        #pragma unroll
        for (int r = 0; r < 4; r++) {
            #pragma unroll
            for (int o = 8; o > 0; o >>= 1) {
                pa[r] += __shfl_down(pa[r], o, 16);
                pr[r] += __shfl_down(pr[r], o, 16);
            }
            if (row == 0) {
                int node = n0 + quad * 4 + r;
                sarr[node] = pa[r];
                rarr[node] = pr[r];
            }
        }
    }
}

// final edge pass: wave-per-4-nodes edge-parallel gather + shfl reduce
__global__ __launch_bounds__(256) void k_last(
        const int* __restrict__ offs, const int* __restrict__ ends,
        const uint32_t* __restrict__ pairs,
        const float* __restrict__ sarr, const float* __restrict__ rarr,
        const float* __restrict__ brelL, float* __restrict__ out) {
    int c = threadIdx.x & 63;
    int w = threadIdx.x >> 6;
    int blk16 = blockIdx.x * 16;
    float b0 = brelL[0];
    #pragma unroll
    for (int t = 0; t < 4; t++) {
        int node = blk16 + w * 4 + t;
        int b = offs[node], e = ends[node];
        float pp = 0.f;
        for (int j = b + c; j < e; j += 64) {
            uint32_t r = pairs[j];
            pp += __uint_as_float((r >> 17) << 16) * sarr[r & 0x1ffffu];
        }
        #pragma unroll
        for (int o = 32; o > 0; o >>= 1) pp += __shfl_down(pp, o, 64);
        if (c == 0) out[node] = pp + rarr[node] + b0;
    }
}

extern "C" void kernel_launch(void* const* d_in, const int* in_sizes, int n_in,
                              void* d_out, int out_size, void* d_ws, size_t ws_size,
                              hipStream_t stream) {
    const float* x        = (const float*)d_in[0];
    const int*   ei       = (const int*)d_in[1];
    const float* ew       = (const float*)d_in[2];
    const float* Wrel0    = (const float*)d_in[3];
    const float* brel0    = (const float*)d_in[4];
    const float* Wroot0   = (const float*)d_in[5];
    const float* Wrel_mid = (const float*)d_in[6];
    const float* brel_mid = (const float*)d_in[7];
    const float* Wroot_mid= (const float*)d_in[8];
    const float* WrelL    = (const float*)d_in[9];
    const float* brelL    = (const float*)d_in[10];
    const float* WrootL   = (const float*)d_in[11];
    float* out = (float*)d_out;

    const int* src  = ei;
    const int* dstp = ei + NE;

    char* w = (char*)d_ws;
    size_t o = 0;
    auto alloc = [&](size_t b) -> void* {
        void* r = (void*)(w + o);
        o += (b + 255) & ~(size_t)255;
        return r;
    };
    int*      offs  = (int*)alloc((size_t)NN * 4);
    int*      ends  = (int*)alloc((size_t)NN * 4);
    int*      bcur  = (int*)alloc((size_t)NBKT * 4);
    uint16_t* WgH   = (uint16_t*)alloc((size_t)3 * 4096 * 2);
    uint16_t* WgL   = (uint16_t*)alloc((size_t)3 * 4096 * 2);
    uint16_t* WrH   = (uint16_t*)alloc((size_t)3 * 4096 * 2);
    uint16_t* WrL   = (uint16_t*)alloc((size_t)3 * 4096 * 2);
    float*    sarr  = (float*)alloc((size_t)NN * 4);
    float*    rarr  = (float*)alloc((size_t)NN * 4);
    float2*   AX    = (float2*)alloc((size_t)NN * 8);            // 0.8 MB
    uint32_t* pairs = (uint32_t*)alloc((size_t)NBKT * CAP * 4);  // 12.8 MB padded
    uint16_t* HbA   = (uint16_t*)alloc((size_t)NN * HID * 2);    // 12.8 MB
    uint16_t* HbB   = (uint16_t*)alloc((size_t)NN * HID * 2);
    uint16_t* spare = (uint16_t*)alloc((size_t)NN * HID * 2);    // bpairs tail
    (void)spare;
    // bpairs (NBKT*CAP*8B = 25.6MB) aliases HbB+spare (contiguous; dead
    // before k_agg1 writes HbB)
    int2*  bpairs = (int2*)HbB;

    // weight split + bucket cursor init (one launch)
    k_wsplit<<<(3 * 4096 + 255) / 256, 256, 0, stream>>>(
        Wrel_mid, Wroot_mid, WgH, WgL, WrH, WrL, bcur);

    // CSR build (padded buckets)
    k_bpart<<<NTILE, 256, 0, stream>>>(src, dstp, ew, bcur, bpairs);
    k_bcsr<<<NBKT, 256, 0, stream>>>(bcur, bpairs, offs, ends, pairs);

    // layer 0: rank-2 state AX = (aggx, x)
    k_l0pre<<<NN / 16, 256, 0, stream>>>(offs, ends, pairs, x, AX);

    int nagg = NN / 16;   // 6250 one-wave blocks, 16 nodes each
    // mid layer 1 (rank-2 input): AX -> h2 rows (weights idx 0)
    k_agg1<<<nagg, 64, 0, stream>>>(
        offs, ends, pairs, AX, Wrel0, brel0, Wroot0,
        WgH, WgL, WrH, WrL, brel_mid, HbB);
    // mid layer 2: h2 -> h3 (weights idx 1)
    k_aggfused<false><<<nagg, 64, 0, stream>>>(
        offs, ends, pairs, HbB,
        WgH + 4096, WgL + 4096, WrH + 4096, WrL + 4096, brel_mid + HID,
        HbA, WrelL, WrootL, sarr, rarr);
    // mid layer 3 (LAST): h3 -> sarr/rarr (weights idx 2)
    k_aggfused<true><<<nagg, 64, 0, stream>>>(
        offs, ends, pairs, HbA,
        WgH + 2 * 4096, WgL + 2 * 4096, WrH + 2 * 4096, WrL + 2 * 4096,
        brel_mid + 2 * HID,
        HbB, WrelL, WrootL, sarr, rarr);

    // final edge pass on scalars
    k_last<<<NN / 16, 256, 0, stream>>>(offs, ends, pairs, sarr, rarr, brelL, out);
}

// Round 14
// 263.677 us; speedup vs baseline: 1.2037x; 1.0645x over previous
//
#include <hip/hip_runtime.h>
#include <stdint.h>

// GraphConv x5 on MI355X — round 33.
// vs round 32 (280.7us; mid layers at the ~47.6us traffic floor; ~145us in
// never-profiled kernels): (1) k_l0pre ELIMINATED — k_bcsr already touches
// every edge during its count pass, so aggx is accumulated there via LDS
// f32 atomicAdd (x gather is L2-resident 400KB) and AX=(aggx,x) is written
// alongside offs/ends. Saves a full pairs re-read + a launch. (2) k_last
// reworked to 16-lane groups (4 nodes concurrently per wave, width-16
// reduce) — old 64-lane loops left 75% of lanes idle at mean degree 16.
// agg1/aggfused/bpart unchanged.

#define NN 100000
#define NE 1600000
#define HID 64
#define NBKT 391            // ceil(NN/256), bucket = dst >> 8
#define CAP 8192            // padded bucket capacity (mean 4092, +64 sigma)
#define PMAX (NBKT * CAP)
#define TILE 4096
#define EPT 16              // TILE / 256
#define NTILE ((NE + TILE - 1) / TILE)   // 391

typedef __attribute__((ext_vector_type(8))) short bf16x8;
typedef __attribute__((ext_vector_type(4))) float f32x4;
typedef __attribute__((ext_vector_type(2))) unsigned int u32x2;
typedef __attribute__((ext_vector_type(4))) unsigned int u32x4;

__device__ __forceinline__ uint32_t rne_bf16(float v) {
    uint32_t u = __float_as_uint(v);
    return (u + 0x7fffu + ((u >> 16) & 1u)) >> 16;
}

// ---------------- CSR build ----------------

// tile-local LDS counting sort + coalesced segment write-out
__global__ __launch_bounds__(256) void k_bpart(const int* __restrict__ src,
                                               const int* __restrict__ dst,
                                               const float* __restrict__ w,
                                               int* __restrict__ bcur,
                                               int2* __restrict__ bpairs) {
    __shared__ int  hcnt[NBKT];      // count, then cursor
    __shared__ int  hoff[NBKT];      // local exclusive offset
    __shared__ int  hadj[NBKT];      // global base - local offset
    __shared__ int  sc0[512];
    __shared__ int  sc1[512];
    __shared__ int2 sT[TILE];        // 32 KB staged tile (bucket-sorted)
    __shared__ int  sAdj[TILE];      // 16 KB per-slot global adjust
    int tile0 = blockIdx.x * TILE;
    int t = threadIdx.x;
    for (int i = t; i < NBKT; i += 256) hcnt[i] = 0;
    __syncthreads();

    int   pk[EPT];
    int   bk[EPT];
    float wv[EPT];
    #pragma unroll
    for (int k = 0; k < EPT; k++) {
        int e = tile0 + t + k * 256;
        if (e < NE) {
            int d = dst[e];
            int b = d >> 8;
            pk[k] = (src[e] << 8) | (d & 255);
            wv[k] = w[e];
            bk[k] = b;
            atomicAdd(&hcnt[b], 1);
        } else {
            bk[k] = -1;
        }
    }
    __syncthreads();

    // inclusive scan of hcnt over 512 (padded) with ping-pong buffers
    sc0[t]       = (t < NBKT) ? hcnt[t] : 0;
    sc0[t + 256] = (t + 256 < NBKT) ? hcnt[t + 256] : 0;
    __syncthreads();
    int* cur = sc0;
    int* oth = sc1;
    for (int off = 1; off < 512; off <<= 1) {
        int v0 = cur[t]       + ((t       >= off) ? cur[t - off]       : 0);
        int v1 = cur[t + 256] + ((t + 256 >= off) ? cur[t + 256 - off] : 0);
        oth[t] = v0;
        oth[t + 256] = v1;
        __syncthreads();
        int* tmp = cur; cur = oth; oth = tmp;
    }
    for (int i = t; i < NBKT; i += 256) {
        int c = hcnt[i];
        int excl = cur[i] - c;
        hoff[i] = excl;
        int gbase = c ? atomicAdd(&bcur[i], c) : 0;
        hadj[i] = gbase - excl;
        hcnt[i] = 0;                 // reuse as local cursor
    }
    __syncthreads();

    // scatter into LDS (bucket-sorted order)
    #pragma unroll
    for (int k = 0; k < EPT; k++) {
        if (bk[k] >= 0) {
            int b = bk[k];
            int pos = hoff[b] + atomicAdd(&hcnt[b], 1);
            sT[pos] = make_int2(pk[k], __float_as_int(wv[k]));
            sAdj[pos] = hadj[b];
        }
    }
    __syncthreads();

    // linear write-out: consecutive slots in a bucket run -> consecutive
    // global addresses (coalesced bursts)
    int n = NE - tile0; if (n > TILE) n = TILE;
    for (int j = t; j < n; j += 256)
        bpairs[sAdj[j] + j] = sT[j];
}

// one block per bucket: stage bucket in LDS, LDS counting sort; FUSED
// layer-0 aggregation (aggx via LDS f32 atomics) -> AX = (aggx, x).
__global__ __launch_bounds__(256) void k_bcsr(const int* __restrict__ bcur,
                                              const int2* __restrict__ bpairs,
                                              const float* __restrict__ x,
                                              int* __restrict__ offs,
                                              int* __restrict__ ends,
                                              uint32_t* __restrict__ pairs,
                                              float2* __restrict__ AX) {
    __shared__ int2 sE[CAP];        // 64 KB bucket stage
    __shared__ int cnt[256];
    __shared__ int scn[256];
    __shared__ int cur[256];
    __shared__ float aggx[256];
    int k = blockIdx.x, t = threadIdx.x;
    int base = k * CAP;
    int scnt = bcur[k] - base;
    cnt[t] = 0;
    aggx[t] = 0.f;
    __syncthreads();
    for (int j = t; j < scnt; j += 256) {
        int2 q = bpairs[base + j];
        sE[j] = q;
        atomicAdd(&cnt[q.x & 255], 1);
        // fused layer-0 contribution: bf16-rounded weight (matches what the
        // mid layers decode from pairs) times gathered x[src]
        uint32_t wb = rne_bf16(__int_as_float(q.y)) & 0x7fffu;
        float wf = __uint_as_float(wb << 16);
        atomicAdd(&aggx[q.x & 255], wf * x[q.x >> 8]);
    }
    __syncthreads();
    int v = cnt[t], acc = v;
    scn[t] = v;
    __syncthreads();
    for (int off = 1; off < 256; off <<= 1) {
        int u = (t >= off) ? scn[t - off] : 0;
        __syncthreads();
        acc += u;
        scn[t] = acc;
        __syncthreads();
    }
    int excl = acc - v;
    cur[t] = excl;
    int d = (k << 8) + t;
    if (d < NN) {
        offs[d] = base + excl;
        ends[d] = base + excl + v;
        AX[d] = make_float2(aggx[t], x[d]);
    }
    __syncthreads();
    for (int j = t; j < scnt; j += 256) {
        int2 q = sE[j];
        int pos = base + atomicAdd(&cur[q.x & 255], 1);
        uint32_t wb = rne_bf16(__int_as_float(q.y)) & 0x7fffu;   // w >= 0
        pairs[pos] = (wb << 17) | (uint32_t)(q.x >> 8);
    }
}

// ---------------- weight hi/lo split (+ bucket cursor init) ----------------

__global__ __launch_bounds__(256) void k_wsplit(const float* __restrict__ Wrel_mid,
                                                const float* __restrict__ Wroot_mid,
                                                uint16_t* __restrict__ WgH,
                                                uint16_t* __restrict__ WgL,
                                                uint16_t* __restrict__ WrH,
                                                uint16_t* __restrict__ WrL,
                                                int* __restrict__ bcur) {
    int i = blockIdx.x * blockDim.x + threadIdx.x;
    if (i < NBKT) bcur[i] = i * CAP;
    if (i >= 3 * 4096) return;
    float a = Wrel_mid[i];
    uint32_t ah = rne_bf16(a);
    float al = a - __uint_as_float(ah << 16);
    WgH[i] = (uint16_t)ah;
    WgL[i] = (uint16_t)rne_bf16(al);
    float b = Wroot_mid[i];
    uint32_t bh = rne_bf16(b);
    float bl = b - __uint_as_float(bh << 16);
    WrH[i] = (uint16_t)bh;
    WrL[i] = (uint16_t)rne_bf16(bl);
}

// ---------------- layers ----------------

// transpose-read, byte-addressed: column = addr bits[6:3], subtile = the
// 128B-aligned base; lane reads bytes (addr&~127) + ((addr>>3)&15)*2 + 32*j
#define TRRA(dst, off) \
    asm volatile("ds_read_b64_tr_b16 %0, %1 offset:" #off \
                 : "=v"(dst) : "v"(trbA))
#define TRRB(dst, off) \
    asm volatile("ds_read_b64_tr_b16 %0, %1 offset:" #off \
                 : "=v"(dst) : "v"(trbB))

// Mid layer 1 (rank-2 input): gather 8B (aggx,x) per edge; redistribute
// via LDS SoA (abuf/xbuf); h1 B-fragments reconstructed with packed
// cvt_pk_bf16; MFMA consume; standard epilogue -> h2 rows.
__global__ __launch_bounds__(64, 4) void k_agg1(
        const int* __restrict__ offs, const int* __restrict__ ends,
        const uint32_t* __restrict__ pairs,
        const float2* __restrict__ AX,
        const float* __restrict__ Wrel0, const float* __restrict__ brel0,
        const float* __restrict__ Wroot0,
        const uint16_t* __restrict__ WgH, const uint16_t* __restrict__ WgL,
        const uint16_t* __restrict__ WrH, const uint16_t* __restrict__ WrL,
        const float* __restrict__ brel,
        uint16_t* __restrict__ Hout) {
    // [0,256) abuf, [256,512) xbuf during the loop; epilogue overlays with
    // sH(2304B) at 0 and sO(2176B) at 2304.
    __shared__ __align__(128) char smem[4608];
    int c = threadIdx.x;                  // 0..63
    int n0 = blockIdx.x * 16;
    int row = c & 15;
    int quad = c >> 4;
    int kq = quad * 8;

    int myNode = n0 + row;
    int blo = offs[myNode];
    int bhi = ends[myNode];
    uint32_t wid = (uint32_t)(bhi - blo);
    int start  = __builtin_amdgcn_readlane(blo, 0);
    int finish = __builtin_amdgcn_readlane(bhi, 15);

    // per-lane B-column weights (col = nb*16 + row)
    float wrc[4], brc[4], woc[4];
    #pragma unroll
    for (int nb = 0; nb < 4; nb++) {
        int col = nb * 16 + row;
        wrc[nb] = Wrel0[col]; brc[nb] = brel0[col]; woc[nb] = Wroot0[col];
    }

    f32x4 acc16[4];
    #pragma unroll
    for (int nb = 0; nb < 4; nb++) acc16[nb] = f32x4{0.f, 0.f, 0.f, 0.f};

    float* abuf = (float*)smem;
    float* xbuf = (float*)(smem + 256);

    int j0 = start + c; if (j0 > PMAX - 1) j0 = PMAX - 1;
    uint32_t praw = pairs[j0];
    uint32_t p = (start + c < finish) ? praw : 0;

    for (int cb = start; cb < finish; cb += 64) {
        int jn = cb + 64 + c; if (jn > PMAX - 1) jn = PMAX - 1;
        uint32_t pr2 = pairs[jn];
        float2 ax = AX[p & 0x1ffffu];     // 8B gather (L2-resident table)
        // A fragments (masked weights) under the load shadow
        uint32_t mA[8], mB[8];
        int dbA = cb + kq - blo;
        int dbB = cb + 32 + kq - blo;
        #pragma unroll
        for (int q = 0; q < 8; q++) {
            uint32_t rq = (uint32_t)__builtin_amdgcn_ds_bpermute(
                (kq + q) * 4, (int)p);
            mA[q] = ((uint32_t)(dbA + q) < wid) ? (rq >> 17) : 0u;
        }
        #pragma unroll
        for (int q = 0; q < 8; q++) {
            uint32_t rq = (uint32_t)__builtin_amdgcn_ds_bpermute(
                (32 + kq + q) * 4, (int)p);
            mB[q] = ((uint32_t)(dbB + q) < wid) ? (rq >> 17) : 0u;
        }
        u32x4 aav = { mA[0] | (mA[1] << 16), mA[2] | (mA[3] << 16),
                      mA[4] | (mA[5] << 16), mA[6] | (mA[7] << 16) };
        u32x4 abv = { mB[0] | (mB[1] << 16), mB[2] | (mB[3] << 16),
                      mB[4] | (mB[5] << 16), mB[6] | (mB[7] << 16) };
        bf16x8 afA = __builtin_bit_cast(bf16x8, aav);
        bf16x8 afB = __builtin_bit_cast(bf16x8, abv);
        asm volatile("s_waitcnt vmcnt(0)" ::: "memory");  // ax + pr2 ready
        // SoA stage: lane writes its edge's (a,x)
        abuf[c] = ax.x;
        xbuf[c] = ax.y;
        asm volatile("s_waitcnt lgkmcnt(0)" ::: "memory");
        __builtin_amdgcn_sched_barrier(0);
        #pragma unroll
        for (int s = 0; s < 2; s++) {
            // lane's 8 edges are contiguous: 2x b128 per array
            f32x4 aL = *(const f32x4*)(smem + s * 128 + kq * 4);
            f32x4 aH = *(const f32x4*)(smem + s * 128 + kq * 4 + 16);
            f32x4 xL = *(const f32x4*)(smem + 256 + s * 128 + kq * 4);
            f32x4 xH = *(const f32x4*)(smem + 256 + s * 128 + kq * 4 + 16);
            asm volatile("s_waitcnt lgkmcnt(0)" ::: "memory");
            __builtin_amdgcn_sched_barrier(0);
            float ar[8], xr[8];
            #pragma unroll
            for (int q = 0; q < 4; q++) {
                ar[q] = aL[q]; ar[q + 4] = aH[q];
                xr[q] = xL[q]; xr[q + 4] = xH[q];
            }
            bf16x8 af = s ? afB : afA;
            #pragma unroll
            for (int nb = 0; nb < 4; nb++) {
                float wr = wrc[nb], br = brc[nb], wo = woc[nb];
                uint32_t bw[4];
                #pragma unroll
                for (int jj = 0; jj < 4; jj++) {
                    float h0 = fmaf(ar[2 * jj], wr, fmaf(xr[2 * jj], wo, br));
                    float h1 = fmaf(ar[2 * jj + 1], wr,
                                    fmaf(xr[2 * jj + 1], wo, br));
                    h0 = h0 > 0.f ? h0 : 0.f;
                    h1 = h1 > 0.f ? h1 : 0.f;
                    asm("v_cvt_pk_bf16_f32 %0, %1, %2"
                        : "=v"(bw[jj]) : "v"(h0), "v"(h1));
                }
                u32x4 bb = { bw[0], bw[1], bw[2], bw[3] };
                acc16[nb] = __builtin_amdgcn_mfma_f32_16x16x32_bf16(
                    af, __builtin_bit_cast(bf16x8, bb), acc16[nb], 0, 0, 0);
            }
        }
        p = (cb + 64 + c < finish) ? pr2 : 0;
    }

    // ---- epilogue: h2 = relu(Wrel1.agg + Wroot1.h1_self + brel1) ----
    // h1_self fragments reconstructed from AX[n0+row]
    float2 axs = AX[n0 + row];
    uint32_t e0[8], e1[8];
    #pragma unroll
    for (int q = 0; q < 8; q++) {
        int k0 = kq + q;
        float h = axs.x * Wrel0[k0] + brel0[k0] + axs.y * Wroot0[k0];
        h = h > 0.f ? h : 0.f;
        e0[q] = rne_bf16(h);
        int k1 = 32 + kq + q;
        float h2 = axs.x * Wrel0[k1] + brel0[k1] + axs.y * Wroot0[k1];
        h2 = h2 > 0.f ? h2 : 0.f;
        e1[q] = rne_bf16(h2);
    }
    u32x4 hv0 = { e0[0] | (e0[1] << 16), e0[2] | (e0[3] << 16),
                  e0[4] | (e0[5] << 16), e0[6] | (e0[7] << 16) };
    u32x4 hv1 = { e1[0] | (e1[1] << 16), e1[2] | (e1[3] << 16),
                  e1[4] | (e1[5] << 16), e1[6] | (e1[7] << 16) };
    bf16x8 hs0 = __builtin_bit_cast(bf16x8, hv0);
    bf16x8 hs1 = __builtin_bit_cast(bf16x8, hv1);

    // pack agg (NO relu) -> sH (overlays abuf/xbuf, now dead)
    uint32_t* sHw = (uint32_t*)smem;
    #pragma unroll
    for (int t = 0; t < 4; t++) {
        #pragma unroll
        for (int nb = 0; nb < 4; nb++) {
            uint32_t hb = rne_bf16(acc16[nb][t]);
            uint32_t pn2 = (uint32_t)__shfl_xor((int)hb, 1, 64);
            if (!(c & 1))
                sHw[(quad * 4 + t) * 36 + nb * 8 + (row >> 1)]
                    = hb | (pn2 << 16);
        }
    }
    asm volatile("s_waitcnt lgkmcnt(0)" ::: "memory");
    __builtin_amdgcn_sched_barrier(0);
    int kb = quad * 8;
    bf16x8 ah0 = *(const bf16x8*)&sHw[row * 36 + quad * 4];
    bf16x8 ah1 = *(const bf16x8*)&sHw[row * 36 + 16 + quad * 4];

    uint16_t* sO = (uint16_t*)(smem + 2304);
    #pragma unroll
    for (int ob = 0; ob < 4; ob++) {
        int oc = ob * 16 + row;
        float bias = brel[oc];
        f32x4 acc = {bias, bias, bias, bias};
        bf16x8 gh0 = *(const bf16x8*)&WgH[oc * 64 + kb];
        bf16x8 gh1 = *(const bf16x8*)&WgH[oc * 64 + 32 + kb];
        bf16x8 gl0 = *(const bf16x8*)&WgL[oc * 64 + kb];
        bf16x8 gl1 = *(const bf16x8*)&WgL[oc * 64 + 32 + kb];
        acc = __builtin_amdgcn_mfma_f32_16x16x32_bf16(ah0, gh0, acc, 0, 0, 0);
        acc = __builtin_amdgcn_mfma_f32_16x16x32_bf16(ah1, gh1, acc, 0, 0, 0);
        acc = __builtin_amdgcn_mfma_f32_16x16x32_bf16(ah0, gl0, acc, 0, 0, 0);
        acc = __builtin_amdgcn_mfma_f32_16x16x32_bf16(ah1, gl1, acc, 0, 0, 0);
        bf16x8 rh0 = *(const bf16x8*)&WrH[oc * 64 + kb];
        bf16x8 rh1 = *(const bf16x8*)&WrH[oc * 64 + 32 + kb];
        bf16x8 rl0 = *(const bf16x8*)&WrL[oc * 64 + kb];
        bf16x8 rl1 = *(const bf16x8*)&WrL[oc * 64 + 32 + kb];
        acc = __builtin_amdgcn_mfma_f32_16x16x32_bf16(hs0, rh0, acc, 0, 0, 0);
        acc = __builtin_amdgcn_mfma_f32_16x16x32_bf16(hs1, rh1, acc, 0, 0, 0);
        acc = __builtin_amdgcn_mfma_f32_16x16x32_bf16(hs0, rl0, acc, 0, 0, 0);
        acc = __builtin_amdgcn_mfma_f32_16x16x32_bf16(hs1, rl1, acc, 0, 0, 0);
        #pragma unroll
        for (int r = 0; r < 4; r++) {
            float v = acc[r] > 0.f ? acc[r] : 0.f;
            sO[(quad * 4 + r) * 68 + oc] = (uint16_t)rne_bf16(v);
        }
    }
    asm volatile("s_waitcnt lgkmcnt(0)" ::: "memory");
    __builtin_amdgcn_sched_barrier(0);
    const uint32_t* sOd = (const uint32_t*)sO;
    uint32_t* Hd = (uint32_t*)Hout;
    #pragma unroll
    for (int it = 0; it < 8; it++) {
        int idx = it * 64 + c;
        int nd = idx >> 5, col = idx & 31;
        Hd[(n0 + nd) * 32 + col] = sOd[nd * 34 + col];
    }
}

// Mid layer (rank-64): gather h rows (r28 schedule), agg via MFMA
// (C-init 0), epilogue h_next = relu(Wrel.agg + Wroot.h_self + brel).
// LAST: epilogue then width-16 shfl dots with WrelL/WrootL -> sarr/rarr.
template <bool LAST>
__global__ __launch_bounds__(64, 5) void k_aggfused(
        const int* __restrict__ offs, const int* __restrict__ ends,
        const uint32_t* __restrict__ pairs,
        const uint16_t* __restrict__ Hb,
        const uint16_t* __restrict__ WgH, const uint16_t* __restrict__ WgL,
        const uint16_t* __restrict__ WrH, const uint16_t* __restrict__ WrL,
        const float* __restrict__ brel,
        uint16_t* __restrict__ Hout,
        const float* __restrict__ WrelL, const float* __restrict__ WrootL,
        float* __restrict__ sarr, float* __restrict__ rarr) {
    __shared__ __align__(128) char smem[8192];
    int c = threadIdx.x;                  // 0..63
    int n0 = blockIdx.x * 16;             // wave owns nodes [n0, n0+16)

    int myNode = n0 + (c & 15);
    int blo = offs[myNode];
    int bhi = ends[myNode];
    uint32_t wid = (uint32_t)(bhi - blo);
    int start  = __builtin_amdgcn_readlane(blo, 0);
    int finish = __builtin_amdgcn_readlane(bhi, 15);

    int kq = (c >> 4) * 8;                // MFMA k-base for this quad
    int eprm  = ((c >> 5) << 2) | ((c >> 1) & 3);
    int lbyte = ((c >> 3) & 3) * 32 + (c & 1) * 16;
    char* stg = smem;                     // chunk A: stg, chunk B: +4096
    uint32_t stgOff = (uint32_t)(uintptr_t)
        (__attribute__((address_space(3))) char*)stg;
    uint32_t trbA = stgOff + ((uint32_t)(c >> 4) << 10)
                          + ((uint32_t)(c & 15) << 3);
    uint32_t trbB = trbA + 4096;

    f32x4 acc16[4];
    #pragma unroll
    for (int nb = 0; nb < 4; nb++) acc16[nb] = f32x4{0.f, 0.f, 0.f, 0.f};

    const char* gbase = (const char*)Hb;
    int j0 = start + c; if (j0 > PMAX - 1) j0 = PMAX - 1;
    uint32_t praw = pairs[j0];
    uint32_t p = (start + c < finish) ? praw : 0;

    for (int cb = start; cb < finish; cb += 64) {
        int jn = cb + 64 + c; if (jn > PMAX - 1) jn = PMAX - 1;
        uint32_t pr2 = pairs[jn];                               // vmem 1
        #pragma unroll
        for (int i = 0; i < 4; i++) {                           // vmem 2-5
            uint32_t r = (uint32_t)__builtin_amdgcn_ds_bpermute(
                (eprm + i * 8) * 4, (int)p);
            uint32_t voff = ((r & 0x1ffffu) << 7) + (uint32_t)lbyte;
            __builtin_amdgcn_global_load_lds(
                (const __attribute__((address_space(1))) void*)(gbase + voff),
                (__attribute__((address_space(3))) void*)(stg + i * 1024),
                16, 0, 0);
        }
        #pragma unroll
        for (int i = 0; i < 4; i++) {                           // vmem 6-9
            uint32_t r = (uint32_t)__builtin_amdgcn_ds_bpermute(
                (32 + eprm + i * 8) * 4, (int)p);
            uint32_t voff = ((r & 0x1ffffu) << 7) + (uint32_t)lbyte;
            __builtin_amdgcn_global_load_lds(
                (const __attribute__((address_space(1))) void*)(gbase + voff),
                (__attribute__((address_space(3))) void*)(stg + 4096 + i * 1024),
                16, 0, 0);
        }
        uint32_t mA[8], mB[8];
        int dbA = cb + kq - blo;
        int dbB = cb + 32 + kq - blo;
        #pragma unroll
        for (int q = 0; q < 8; q++) {
            uint32_t rq = (uint32_t)__builtin_amdgcn_ds_bpermute(
                (kq + q) * 4, (int)p);
            mA[q] = ((uint32_t)(dbA + q) < wid) ? (rq >> 17) : 0u;
        }
        #pragma unroll
        for (int q = 0; q < 8; q++) {
            uint32_t rq = (uint32_t)__builtin_amdgcn_ds_bpermute(
                (32 + kq + q) * 4, (int)p);
            mB[q] = ((uint32_t)(dbB + q) < wid) ? (rq >> 17) : 0u;
        }
        u32x4 aav = { mA[0] | (mA[1] << 16), mA[2] | (mA[3] << 16),
                      mA[4] | (mA[5] << 16), mA[6] | (mA[7] << 16) };
        u32x4 abv = { mB[0] | (mB[1] << 16), mB[2] | (mB[3] << 16),
                      mB[4] | (mB[5] << 16), mB[6] | (mB[7] << 16) };
        bf16x8 afA = __builtin_bit_cast(bf16x8, aav);
        bf16x8 afB = __builtin_bit_cast(bf16x8, abv);
        asm volatile("s_waitcnt vmcnt(4)" ::: "memory");
        {
            u32x2 tb0, tb1, tb2, tb3, tb4, tb5, tb6, tb7;
            TRRA(tb0, 0);   TRRA(tb1, 512);
            TRRA(tb2, 128); TRRA(tb3, 640);
            TRRA(tb4, 256); TRRA(tb5, 768);
            TRRA(tb6, 384); TRRA(tb7, 896);
            asm volatile("s_waitcnt lgkmcnt(0)" ::: "memory");
            __builtin_amdgcn_sched_barrier(0);
            u32x4 bb0 = { tb0.x, tb0.y, tb1.x, tb1.y };
            acc16[0] = __builtin_amdgcn_mfma_f32_16x16x32_bf16(
                afA, __builtin_bit_cast(bf16x8, bb0), acc16[0], 0, 0, 0);
            u32x4 bb1 = { tb2.x, tb2.y, tb3.x, tb3.y };
            acc16[1] = __builtin_amdgcn_mfma_f32_16x16x32_bf16(
                afA, __builtin_bit_cast(bf16x8, bb1), acc16[1], 0, 0, 0);
            u32x4 bb2 = { tb4.x, tb4.y, tb5.x, tb5.y };
            acc16[2] = __builtin_amdgcn_mfma_f32_16x16x32_bf16(
                afA, __builtin_bit_cast(bf16x8, bb2), acc16[2], 0, 0, 0);
            u32x4 bb3 = { tb6.x, tb6.y, tb7.x, tb7.y };
            acc16[3] = __builtin_amdgcn_mfma_f32_16x16x32_bf16(
                afA, __builtin_bit_cast(bf16x8, bb3), acc16[3], 0, 0, 0);
        }
        asm volatile("s_waitcnt vmcnt(0)" ::: "memory");
        {
            u32x2 tb0, tb1, tb2, tb3, tb4, tb5, tb6, tb7;
            TRRB(tb0, 0);   TRRB(tb1, 512);
            TRRB(tb2, 128); TRRB(tb3, 640);
            TRRB(tb4, 256); TRRB(tb5, 768);
            TRRB(tb6, 384); TRRB(tb7, 896);
            asm volatile("s_waitcnt lgkmcnt(0)" ::: "memory");
            __builtin_amdgcn_sched_barrier(0);
            u32x4 bb0 = { tb0.x, tb0.y, tb1.x, tb1.y };
            acc16[0] = __builtin_amdgcn_mfma_f32_16x16x32_bf16(
                afB, __builtin_bit_cast(bf16x8, bb0), acc16[0], 0, 0, 0);
            u32x4 bb1 = { tb2.x, tb2.y, tb3.x, tb3.y };
            acc16[1] = __builtin_amdgcn_mfma_f32_16x16x32_bf16(
                afB, __builtin_bit_cast(bf16x8, bb1), acc16[1], 0, 0, 0);
            u32x4 bb2 = { tb4.x, tb4.y, tb5.x, tb5.y };
            acc16[2] = __builtin_amdgcn_mfma_f32_16x16x32_bf16(
                afB, __builtin_bit_cast(bf16x8, bb2), acc16[2], 0, 0, 0);
            u32x4 bb3 = { tb6.x, tb6.y, tb7.x, tb7.y };
            acc16[3] = __builtin_amdgcn_mfma_f32_16x16x32_bf16(
                afB, __builtin_bit_cast(bf16x8, bb3), acc16[3], 0, 0, 0);
        }
        p = (cb + 64 + c < finish) ? pr2 : 0;
    }
    asm volatile("s_waitcnt vmcnt(0)" ::: "memory");

    // ---- shared epilogue: h' = Wrel.agg + Wroot.h_self + brel ----
    int row = c & 15;
    int quad = c >> 4;
    int kb = quad * 8;
    bf16x8 hs0 = *(const bf16x8*)&Hb[(n0 + row) * 64 + kb];
    bf16x8 hs1 = *(const bf16x8*)&Hb[(n0 + row) * 64 + 32 + kb];
    uint32_t* sHw = (uint32_t*)smem;
    #pragma unroll
    for (int t = 0; t < 4; t++) {
        #pragma unroll
        for (int nb = 0; nb < 4; nb++) {
            uint32_t hb = rne_bf16(acc16[nb][t]);
            uint32_t pn2 = (uint32_t)__shfl_xor((int)hb, 1, 64);
            if (!(c & 1))
                sHw[(quad * 4 + t) * 36 + nb * 8 + (row >> 1)]
                    = hb | (pn2 << 16);
        }
    }
    asm volatile("s_waitcnt lgkmcnt(0)" ::: "memory");
    __builtin_amdgcn_sched_barrier(0);
    bf16x8 ah0 = *(const bf16x8*)&sHw[row * 36 + quad * 4];
    bf16x8 ah1 = *(const bf16x8*)&sHw[row * 36 + 16 + quad * 4];

    if (!LAST) {
        uint16_t* sO = (uint16_t*)(smem + 2304);
        #pragma unroll
        for (int ob = 0; ob < 4; ob++) {
            int oc = ob * 16 + row;
            float bias = brel[oc];
            f32x4 acc = {bias, bias, bias, bias};
            bf16x8 gh0 = *(const bf16x8*)&WgH[oc * 64 + kb];
            bf16x8 gh1 = *(const bf16x8*)&WgH[oc * 64 + 32 + kb];
            bf16x8 gl0 = *(const bf16x8*)&WgL[oc * 64 + kb];
            bf16x8 gl1 = *(const bf16x8*)&WgL[oc * 64 + 32 + kb];
            acc = __builtin_amdgcn_mfma_f32_16x16x32_bf16(ah0, gh0, acc, 0, 0, 0);
            acc = __builtin_amdgcn_mfma_f32_16x16x32_bf16(ah1, gh1, acc, 0, 0, 0);
            acc = __builtin_amdgcn_mfma_f32_16x16x32_bf16(ah0, gl0, acc, 0, 0, 0);
            acc = __builtin_amdgcn_mfma_f32_16x16x32_bf16(ah1, gl1, acc, 0, 0, 0);
            bf16x8 rh0 = *(const bf16x8*)&WrH[oc * 64 + kb];
            bf16x8 rh1 = *(const bf16x8*)&WrH[oc * 64 + 32 + kb];
            bf16x8 rl0 = *(const bf16x8*)&WrL[oc * 64 + kb];
            bf16x8 rl1 = *(const bf16x8*)&WrL[oc * 64 + 32 + kb];
            acc = __builtin_amdgcn_mfma_f32_16x16x32_bf16(hs0, rh0, acc, 0, 0, 0);
            acc = __builtin_amdgcn_mfma_f32_16x16x32_bf16(hs1, rh1, acc, 0, 0, 0);
            acc = __builtin_amdgcn_mfma_f32_16x16x32_bf16(hs0, rl0, acc, 0, 0, 0);
            acc = __builtin_amdgcn_mfma_f32_16x16x32_bf16(hs1, rl1, acc, 0, 0, 0);
            #pragma unroll
            for (int r = 0; r < 4; r++) {
                float v = acc[r] > 0.f ? acc[r] : 0.f;
                sO[(quad * 4 + r) * 68 + oc] = (uint16_t)rne_bf16(v);
            }
        }
        asm volatile("s_waitcnt lgkmcnt(0)" ::: "memory");
        __builtin_amdgcn_sched_barrier(0);
        const uint32_t* sOd = (const uint32_t*)sO;
        uint32_t* Hd = (uint32_t*)Hout;
        #pragma unroll
        for (int it = 0; it < 8; it++) {
            int idx = it * 64 + c;
            int nd = idx >> 5, col = idx & 31;
            Hd[(n0 + nd) * 32 + col] = sOd[nd * 34 + col];
        }
    } else {
        float pa[4] = {0.f, 0.f, 0.f, 0.f};
        float pr[4] = {0.f, 0.f, 0.f, 0.f};
        #pragma unroll
        for (int ob = 0; ob < 4; ob++) {
            int oc = ob * 16 + row;
            float bias = brel[oc];
            f32x4 acc = {bias, bias, bias, bias};
            bf16x8 gh0 = *(const bf16x8*)&WgH[oc * 64 + kb];
            bf16x8 gh1 = *(const bf16x8*)&WgH[oc * 64 + 32 + kb];
            bf16x8 gl0 = *(const bf16x8*)&WgL[oc * 64 + kb];
            bf16x8 gl1 = *(const bf16x8*)&WgL[oc * 64 + 32 + kb];
            acc = __builtin_amdgcn_mfma_f32_16x16x32_bf16(ah0, gh0, acc, 0, 0, 0);
            acc = __builtin_amdgcn_mfma_f32_16x16x32_bf16(ah1, gh1, acc, 0, 0, 0);
            acc = __builtin_amdgcn_mfma_f32_16x16x32_bf16(ah0, gl0, acc, 0, 0, 0);
            acc = __builtin_amdgcn_mfma_f32_16x16x32_bf16(ah1, gl1, acc, 0, 0, 0);
            bf16x8 rh0 = *(const bf16x8*)&WrH[oc * 64 + kb];
            bf16x8 rh1 = *(const bf16x8*)&WrH[oc * 64 + 32 + kb];
            bf16x8 rl0 = *(const bf16x8*)&WrL[oc * 64 + kb];
            bf16x8 rl1 = *(const bf16x8*)&WrL[oc * 64 + 32 + kb];
            acc = __builtin_amdgcn_mfma_f32_16x16x32_bf16(hs0, rh0, acc, 0, 0, 0);
            acc = __builtin_amdgcn_mfma_f32_16x16x32_bf16(hs1, rh1, acc, 0, 0, 0);
            acc = __builtin_amdgcn_mfma_f32_16x16x32_bf16(hs0, rl0, acc, 0, 0, 0);
            acc = __builtin_amdgcn_mfma_f32_16x16x32_bf16(hs1, rl1, acc, 0, 0, 0);
            float wlc = WrelL[oc], woc = WrootL[oc];
            #pragma unroll
            for (int r = 0; r < 4; r++) {
                float v = acc[r] > 0.f ? acc[r] : 0.f;
                pa[r] += v * wlc;
                pr[r] += v * woc;
            }
        }
        #pragma unroll
        for (int r = 0; r < 4; r++) {
            #pragma unroll
            for (int o = 8; o > 0; o >>= 1) {
                pa[r] += __shfl_down(pa[r], o, 16);
                pr[r] += __shfl_down(pr[r], o, 16);
            }
            if (row == 0) {
                int node = n0 + quad * 4 + r;
                sarr[node] = pa[r];
                rarr[node] = pr[r];
            }
        }
    }
}

// final edge pass: 16-lane groups — 4 nodes concurrently per wave, full
// lane utilization at mean degree 16 (was 64-lane loops, 75% idle).
__global__ __launch_bounds__(256) void k_last(
        const int* __restrict__ offs, const int* __restrict__ ends,
        const uint32_t* __restrict__ pairs,
        const float* __restrict__ sarr, const float* __restrict__ rarr,
        const float* __restrict__ brelL, float* __restrict__ out) {
    int c = threadIdx.x & 63;
    int w = threadIdx.x >> 6;
    int g = c >> 4;                  // group 0-3 within wave
    int l = c & 15;                  // lane within group
    int node = blockIdx.x * 16 + w * 4 + g;
    float b0 = brelL[0];
    int b = offs[node], e = ends[node];
    float pp = 0.f;
    for (int j = b + l; j < e; j += 16) {
        uint32_t r = pairs[j];
        pp += __uint_as_float((r >> 17) << 16) * sarr[r & 0x1ffffu];
    }
    #pragma unroll
    for (int o = 8; o > 0; o >>= 1) pp += __shfl_down(pp, o, 16);
    if (l == 0) out[node] = pp + rarr[node] + b0;
}

extern "C" void kernel_launch(void* const* d_in, const int* in_sizes, int n_in,
                              void* d_out, int out_size, void* d_ws, size_t ws_size,
                              hipStream_t stream) {
    const float* x        = (const float*)d_in[0];
    const int*   ei       = (const int*)d_in[1];
    const float* ew       = (const float*)d_in[2];
    const float* Wrel0    = (const float*)d_in[3];
    const float* brel0    = (const float*)d_in[4];
    const float* Wroot0   = (const float*)d_in[5];
    const float* Wrel_mid = (const float*)d_in[6];
    const float* brel_mid = (const float*)d_in[7];
    const float* Wroot_mid= (const float*)d_in[8];
    const float* WrelL    = (const float*)d_in[9];
    const float* brelL    = (const float*)d_in[10];
    const float* WrootL   = (const float*)d_in[11];
    float* out = (float*)d_out;

    const int* src  = ei;
    const int* dstp = ei + NE;

    char* w = (char*)d_ws;
    size_t o = 0;
    auto alloc = [&](size_t b) -> void* {
        void* r = (void*)(w + o);
        o += (b + 255) & ~(size_t)255;
        return r;
    };
    int*      offs  = (int*)alloc((size_t)NN * 4);
    int*      ends  = (int*)alloc((size_t)NN * 4);
    int*      bcur  = (int*)alloc((size_t)NBKT * 4);
    uint16_t* WgH   = (uint16_t*)alloc((size_t)3 * 4096 * 2);
    uint16_t* WgL   = (uint16_t*)alloc((size_t)3 * 4096 * 2);
    uint16_t* WrH   = (uint16_t*)alloc((size_t)3 * 4096 * 2);
    uint16_t* WrL   = (uint16_t*)alloc((size_t)3 * 4096 * 2);
    float*    sarr  = (float*)alloc((size_t)NN * 4);
    float*    rarr  = (float*)alloc((size_t)NN * 4);
    float2*   AX    = (float2*)alloc((size_t)NN * 8);            // 0.8 MB
    uint32_t* pairs = (uint32_t*)alloc((size_t)NBKT * CAP * 4);  // 12.8 MB padded
    uint16_t* HbA   = (uint16_t*)alloc((size_t)NN * HID * 2);    // 12.8 MB
    uint16_t* HbB   = (uint16_t*)alloc((size_t)NN * HID * 2);
    uint16_t* spare = (uint16_t*)alloc((size_t)NN * HID * 2);    // bpairs tail
    (void)spare;
    // bpairs (NBKT*CAP*8B = 25.6MB) aliases HbB+spare (contiguous; dead
    // before k_agg1 writes HbB)
    int2*  bpairs = (int2*)HbB;

    // weight split + bucket cursor init (one launch)
    k_wsplit<<<(3 * 4096 + 255) / 256, 256, 0, stream>>>(
        Wrel_mid, Wroot_mid, WgH, WgL, WrH, WrL, bcur);

    // CSR build (padded buckets) + fused layer-0 aggregation -> AX
    k_bpart<<<NTILE, 256, 0, stream>>>(src, dstp, ew, bcur, bpairs);
    k_bcsr<<<NBKT, 256, 0, stream>>>(bcur, bpairs, x, offs, ends, pairs, AX);

    int nagg = NN / 16;   // 6250 one-wave blocks, 16 nodes each
    // mid layer 1 (rank-2 input): AX -> h2 rows (weights idx 0)
    k_agg1<<<nagg, 64, 0, stream>>>(
        offs, ends, pairs, AX, Wrel0, brel0, Wroot0,
        WgH, WgL, WrH, WrL, brel_mid, HbB);
    // mid layer 2: h2 -> h3 (weights idx 1)
    k_aggfused<false><<<nagg, 64, 0, stream>>>(
        offs, ends, pairs, HbB,
        WgH + 4096, WgL + 4096, WrH + 4096, WrL + 4096, brel_mid + HID,
        HbA, WrelL, WrootL, sarr, rarr);
    // mid layer 3 (LAST): h3 -> sarr/rarr (weights idx 2)
    k_aggfused<true><<<nagg, 64, 0, stream>>>(
        offs, ends, pairs, HbA,
        WgH + 2 * 4096, WgL + 2 * 4096, WrH + 2 * 4096, WrL + 2 * 4096,
        brel_mid + 2 * HID,
        HbB, WrelL, WrootL, sarr, rarr);

    // final edge pass on scalars (16 nodes/block)
    k_last<<<NN / 16, 256, 0, stream>>>(offs, ends, pairs, sarr, rarr, brelL, out);
}